// Round 7
// baseline (1107.102 us; speedup 1.0000x reference)
//
#include <hip/hip_runtime.h>
#include <cmath>

constexpr int BB = 8, TT = 96, EE = 96, CC = 256, HHD = 8, DDm = 32;
constexpr int NTOK = BB * TT * EE;   // 73728
constexpr int TOUT = TT / 2;         // 48

typedef unsigned short u16;
typedef short bf16x8 __attribute__((ext_vector_type(8)));
typedef float f32x4 __attribute__((ext_vector_type(4)));

__device__ __forceinline__ float bf2f(u16 u) {
  union { unsigned int i; float f; } v; v.i = ((unsigned int)u) << 16; return v.f;
}
__device__ __forceinline__ u16 f2bf(float f) {
  union { unsigned int i; float f; } v; v.f = f;
  return (u16)((v.i + 0x7FFFu + ((v.i >> 16) & 1u)) >> 16);  // RNE
}
__device__ __forceinline__ float wsum(float v) {
#pragma unroll
  for (int off = 32; off; off >>= 1) v += __shfl_xor(v, off);
  return v;
}
__device__ __forceinline__ float gelu_f(float x) {
  return 0.5f * x * (1.0f + erff(x * 0.70710678118654752f));
}
// token-order permutations: 0=id, 1=[b,t,e]->[b,e,t] position, 2=[b,e,t]->[b,t,e]
__device__ __forceinline__ int remap_row(int row, int mode) {
  if (mode == 0) return row;
  int b = row / (TT * EE);
  int rem = row - b * (TT * EE);
  if (mode == 1) { int t = rem / EE, e = rem - t * EE; return (b * EE + e) * TT + t; }
  int e = rem / TT, t = rem - e * TT;
  return (b * TT + t) * EE + e;
}

// -------- batched weight transpose+convert: 8 x [256,256] fp32 -> bf16 [Nc][K] --------
struct WPtr8 { const float* p[8]; };
__global__ void k_transpose8(WPtr8 src, u16* __restrict__ dst) {
  const float* in = src.p[blockIdx.y];
  u16* out = dst + (size_t)blockIdx.y * 65536;
  int idx = blockIdx.x * 256 + threadIdx.x;
  int k = idx >> 8, c = idx & 255;
  out[c * 256 + k] = f2bf(in[idx]);
}

// -------- weight transpose+convert: W fp32 [K][Nc] -> Wt bf16 [Nc][K] --------
__global__ void k_transpose(const float* __restrict__ in, u16* __restrict__ out, int K, int Nc, int n) {
  int idx = blockIdx.x * 256 + threadIdx.x;
  if (idx < n) {
    int k = idx / Nc, c = idx - k * Nc;
    out[c * K + k] = f2bf(in[idx]);
  }
}

// -------- fp32 -> bf16 convert (adj) --------
__global__ void k_cvt(const float* __restrict__ in, u16* __restrict__ out, int n) {
  int idx = blockIdx.x * 256 + threadIdx.x;
  if (idx < n) out[idx] = f2bf(in[idx]);
}

// ------- LN of fp32 input x -> A = LN(x)*g+b (bf16); no X copy -------
__global__ __launch_bounds__(256) void k_ln_in(const float* __restrict__ x,
                                               u16* __restrict__ A, const float* __restrict__ g,
                                               const float* __restrict__ b) {
  int wv = threadIdx.x >> 6, lane = threadIdx.x & 63;
  long tok = (long)blockIdx.x * 4 + wv;
  int c = lane * 4;
  long off = tok * CC + c;
  float4 v = *(const float4*)(x + off);
  float s = v.x + v.y + v.z + v.w;
  float sq = v.x * v.x + v.y * v.y + v.z * v.z + v.w * v.w;
  s = wsum(s); sq = wsum(sq);
  float m = s * (1.0f / CC);
  float rs = rsqrtf(sq * (1.0f / CC) - m * m + 1e-5f);
  float4 gv = *(const float4*)(g + c);
  float4 bv = *(const float4*)(b + c);
  ushort4 o;
  o.x = f2bf((v.x - m) * rs * gv.x + bv.x);
  o.y = f2bf((v.y - m) * rs * gv.y + bv.y);
  o.z = f2bf((v.z - m) * rs * gv.z + bv.z);
  o.w = f2bf((v.w - m) * rs * gv.w + bv.w);
  *(ushort4*)(A + off) = o;
}

// ---------------- A = LN(X fp32)*g+b ----------------
__global__ __launch_bounds__(256) void k_ln_f32(const float* __restrict__ X, u16* __restrict__ A,
                                                const float* __restrict__ g, const float* __restrict__ b) {
  int wv = threadIdx.x >> 6, lane = threadIdx.x & 63;
  long tok = (long)blockIdx.x * 4 + wv;
  int c = lane * 4;
  long off = tok * CC + c;
  float4 v = *(const float4*)(X + off);
  float s = v.x + v.y + v.z + v.w;
  float sq = v.x * v.x + v.y * v.y + v.z * v.z + v.w * v.w;
  s = wsum(s); sq = wsum(sq);
  float m = s * (1.0f / CC);
  float rs = rsqrtf(sq * (1.0f / CC) - m * m + 1e-5f);
  float4 gv = *(const float4*)(g + c);
  float4 bv = *(const float4*)(b + c);
  ushort4 o;
  o.x = f2bf((v.x - m) * rs * gv.x + bv.x);
  o.y = f2bf((v.y - m) * rs * gv.y + bv.y);
  o.z = f2bf((v.z - m) * rs * gv.z + bv.z);
  o.w = f2bf((v.w - m) * rs * gv.w + bv.w);
  *(ushort4*)(A + off) = o;
}

// ------- spatial combine: reads pristine x; xs = LN1(x); o = LN(P)*s_ng+s_nb;
//         X = x + xs + s_gamma*o (first write of X); A = LN2(X) -------
__global__ __launch_bounds__(256) void k_sp_combine(const float* __restrict__ xin, float* __restrict__ X,
                                                    u16* __restrict__ A, const u16* __restrict__ P,
                                                    const float* __restrict__ n1g, const float* __restrict__ n1b,
                                                    const float* __restrict__ sg,
                                                    const float* __restrict__ s_ng, const float* __restrict__ s_nb,
                                                    const float* __restrict__ n2g, const float* __restrict__ n2b) {
  int wv = threadIdx.x >> 6, lane = threadIdx.x & 63;
  long tok = (long)blockIdx.x * 4 + wv;
  int c = lane * 4;
  long off = tok * CC + c;
  float4 xv = *(const float4*)(xin + off);
  float s1 = xv.x + xv.y + xv.z + xv.w;
  float q1 = xv.x * xv.x + xv.y * xv.y + xv.z * xv.z + xv.w * xv.w;
  s1 = wsum(s1); q1 = wsum(q1);
  float m1 = s1 * (1.0f / CC);
  float r1 = rsqrtf(q1 * (1.0f / CC) - m1 * m1 + 1e-5f);
  float4 g1 = *(const float4*)(n1g + c);
  float4 b1 = *(const float4*)(n1b + c);
  float xs0 = (xv.x - m1) * r1 * g1.x + b1.x;
  float xs1 = (xv.y - m1) * r1 * g1.y + b1.y;
  float xs2 = (xv.z - m1) * r1 * g1.z + b1.z;
  float xs3 = (xv.w - m1) * r1 * g1.w + b1.w;
  ushort4 up = *(const ushort4*)(P + off);
  float4 p = make_float4(bf2f(up.x), bf2f(up.y), bf2f(up.z), bf2f(up.w));
  float s = p.x + p.y + p.z + p.w;
  float sq = p.x * p.x + p.y * p.y + p.z * p.z + p.w * p.w;
  s = wsum(s); sq = wsum(sq);
  float m = s * (1.0f / CC);
  float rs = rsqrtf(sq * (1.0f / CC) - m * m + 1e-5f);
  float4 ug = *(const float4*)(s_ng + c);
  float4 ub = *(const float4*)(s_nb + c);
  float o0 = (p.x - m) * rs * ug.x + ub.x;
  float o1 = (p.y - m) * rs * ug.y + ub.y;
  float o2 = (p.z - m) * rs * ug.z + ub.z;
  float o3 = (p.w - m) * rs * ug.w + ub.w;
  float gsg = sg[0];
  float x0 = xv.x + xs0 + gsg * o0;
  float x1 = xv.y + xs1 + gsg * o1;
  float x2 = xv.z + xs2 + gsg * o2;
  float x3 = xv.w + xs3 + gsg * o3;
  *(float4*)(X + off) = make_float4(x0, x1, x2, x3);
  float s2 = x0 + x1 + x2 + x3;
  float sq2 = x0 * x0 + x1 * x1 + x2 * x2 + x3 * x3;
  s2 = wsum(s2); sq2 = wsum(sq2);
  float m2 = s2 * (1.0f / CC);
  float rs2 = rsqrtf(sq2 * (1.0f / CC) - m2 * m2 + 1e-5f);
  float4 g2 = *(const float4*)(n2g + c);
  float4 b2 = *(const float4*)(n2b + c);
  ushort4 o;
  o.x = f2bf((x0 - m2) * rs2 * g2.x + b2.x);
  o.y = f2bf((x1 - m2) * rs2 * g2.y + b2.y);
  o.z = f2bf((x2 - m2) * rs2 * g2.z + b2.z);
  o.w = f2bf((x3 - m2) * rs2 * g2.w + b2.w);
  *(ushort4*)(A + off) = o;
}

// ---- 256x256-tile 8-wave phase-scheduled MFMA GEMM (m201-template port) ----
// out[M,Nc] = act[M,Kd](lda) @ Wt[Nc,Kd](ldb)^T. 512 thr = 8 waves (2M x 4N), per-wave 128x64 out.
// BK=64, 2 x 64KB LDS dbuf (128 KB, 1 blk/CU). Per K-tile: full-tile prefetch at top (8 loads/thr,
// >=512cy MFMA cover >= L2 latency), then 4 phases {A-frag ds_read | barrier | lgkm(0) |
// setprio+16 MFMA | barrier} -> waves counter-phase (T3+T5); end-of-tile vmcnt(0)+barrier.
// 8-slot XOR swizzle slot^(row&7), rule-21 both-sides; read pattern 2-way/bank = free (m136).
// Accumulation is K-ascending in 32-chunks -> bitwise identical to previous 128x128 kernel.
// epi: 0 plain; 1 +bias; 2 +bias,gelu; 3 (+bias), Xacc += gamma*val (LDS-staged, float4 RMW).
__global__ __launch_bounds__(512, 2) void k_gemm256(const u16* __restrict__ act, const u16* __restrict__ Wt,
                                                    const float* __restrict__ bias, const float* __restrict__ gptr,
                                                    u16* __restrict__ outB, float* __restrict__ Xacc,
                                                    int Kd, int Nc, int lda, int ldb, int epi, int remap) {
  __shared__ __align__(16) u16 smem[2 * 32768];   // 131072 B: 2 x (As[256][64] | Bs[256][64]); epilogue aliases
  int gx = gridDim.x;
  int nwg = gx * gridDim.y;
  int lid = blockIdx.y * gx + blockIdx.x;
  if ((nwg & 7) == 0) lid = (lid & 7) * (nwg >> 3) + (lid >> 3);  // XCD-chunked (all grids %8==0)
  int m0 = (lid / gx) * 256, n0 = (lid % gx) * 256;
  int tid = threadIdx.x;
  int wid = tid >> 6, lane = tid & 63, lm = lane & 15, quad = lane >> 4;
  int wm = wid >> 2, wn = wid & 3;                 // wave grid 2(M) x 4(N)
  f32x4 acc[8][4];
#pragma unroll
  for (int i = 0; i < 8; i++)
#pragma unroll
    for (int j = 0; j < 4; j++) acc[i][j] = (f32x4){0.f, 0.f, 0.f, 0.f};

  // staging: per j, wave-uniform LDS dest (row j*64+wid*8, slot 0); HW adds lane*16B ->
  // row += lane>>3, slot = lane&7 (linear). Global source per-lane, slot pre-swizzled by row&7.
  int srow = wid * 8 + (lane >> 3);                // = tid>>3
  int swsl = (lane & 7) ^ (lane >> 3);             // (row&7) == lane>>3 for all j (j*64 = 0 mod 8)
  const u16* pa = act + (long)(m0 + srow) * lda + swsl * 8;
  const u16* pb = Wt + (long)(n0 + srow) * ldb + swsl * 8;

  auto STAGE = [&](int buf, int kk) {
    u16* sb = smem + buf * 32768;
#pragma unroll
    for (int j = 0; j < 4; j++) {
      __builtin_amdgcn_global_load_lds(pa + (long)(j * 64) * lda + kk, sb + (j * 64 + wid * 8) * 64, 16, 0, 0);
      __builtin_amdgcn_global_load_lds(pb + (long)(j * 64) * ldb + kk, sb + 16384 + (j * 64 + wid * 8) * 64, 16, 0, 0);
    }
  };

  int NT = Kd >> 6;                                // 4 (K=256) or 16 (K=1024)
  STAGE(0, 0);
  asm volatile("s_waitcnt vmcnt(0)" ::: "memory");
  __builtin_amdgcn_sched_barrier(0);
  __builtin_amdgcn_s_barrier();

  int swk = lm & 7;                                // read swizzle key: frag rows are 16*x+lm -> row&7 = lm&7
  int cur = 0;
  for (int t = 0; t < NT; ++t) {
    if (t + 1 < NT) STAGE(cur ^ 1, (t + 1) << 6);  // full-tile prefetch at tile top
    const u16* As = smem + cur * 32768;
    const u16* Bs = As + 16384;
    bf16x8 bfr[4][2];                              // B frags for whole tile (4 nf x 2 ks)
#pragma unroll
    for (int nf = 0; nf < 4; nf++)
#pragma unroll
      for (int ks = 0; ks < 2; ks++)
        bfr[nf][ks] = *(const bf16x8*)&Bs[(wn * 64 + nf * 16 + lm) * 64 + (((ks * 4 + quad) ^ swk) * 8)];
#pragma unroll
    for (int p = 0; p < 4; p++) {                  // phase p: fragment rows {2p, 2p+1}
      bf16x8 af[2][2];
#pragma unroll
      for (int mi = 0; mi < 2; mi++)
#pragma unroll
        for (int ks = 0; ks < 2; ks++)
          af[mi][ks] = *(const bf16x8*)&As[(wm * 128 + (p * 2 + mi) * 16 + lm) * 64 + (((ks * 4 + quad) ^ swk) * 8)];
      __builtin_amdgcn_s_barrier();                // waves counter-phase: my ds_read vs others' MFMA
      asm volatile("s_waitcnt lgkmcnt(0)" ::: "memory");
      __builtin_amdgcn_sched_barrier(0);           // rule-18: don't hoist MFMA past the wait
      __builtin_amdgcn_s_setprio(1);
#pragma unroll
      for (int ks = 0; ks < 2; ks++)
#pragma unroll
        for (int mi = 0; mi < 2; mi++)
#pragma unroll
          for (int nf = 0; nf < 4; nf++)
            acc[p * 2 + mi][nf] = __builtin_amdgcn_mfma_f32_16x16x32_bf16(af[mi][ks], bfr[nf][ks],
                                                                          acc[p * 2 + mi][nf], 0, 0, 0);
      __builtin_amdgcn_s_setprio(0);
      if (p < 3) __builtin_amdgcn_s_barrier();
    }
    asm volatile("s_waitcnt vmcnt(0)" ::: "memory");   // next tile landed (issued a full tile ago)
    __builtin_amdgcn_sched_barrier(0);
    __builtin_amdgcn_s_barrier();
    cur ^= 1;
  }

  // ---- epilogue: C rows = m0 + wm*128 + mf*16 + quad*4 + r; cols = n0 + wn*64 + nf*16 + lm ----
  if (epi == 3) {
    float gm = gptr ? gptr[0] : 1.0f;
    float* fs = (float*)smem;                      // 64 x 264 fp32 = 67.6 KB
#pragma unroll
    for (int qp = 0; qp < 4; qp++) {               // row quarter qp*64 .. +63
      if (qp) __syncthreads();
      if (wm == (qp >> 1)) {
        int mfb = (qp & 1) * 4;
#pragma unroll
        for (int nf = 0; nf < 4; nf++) {
          int col = wn * 64 + nf * 16 + lm;
          float bv = bias ? bias[n0 + col] : 0.0f;
#pragma unroll
          for (int mi = 0; mi < 4; mi++)
#pragma unroll
            for (int r = 0; r < 4; r++)
              fs[(mi * 16 + quad * 4 + r) * 264 + col] = gm * (acc[mfb + mi][nf][r] + bv);
        }
      }
      __syncthreads();
#pragma unroll
      for (int p2 = 0; p2 < 8; p2++) {             // 64 rows x 64 float4 chunks = 4096
        int idx = p2 * 512 + tid;
        int lrow = idx >> 6, c4 = idx & 63;
        int grow = remap_row(m0 + qp * 64 + lrow, remap);
        float* gp = Xacc + (long)grow * Nc + n0 + c4 * 4;
        float4 xv = *(float4*)gp;
        float4 sv = *(const float4*)&fs[lrow * 264 + c4 * 4];
        xv.x += sv.x; xv.y += sv.y; xv.z += sv.z; xv.w += sv.w;
        *(float4*)gp = xv;
      }
    }
  } else {
    u16* fs = smem;                                // 128 x 264 u16 = 67.6 KB per half
#pragma unroll
    for (int h = 0; h < 2; h++) {                  // row half h*128 .. +127
      if (h) __syncthreads();
      if (wm == h) {
#pragma unroll
        for (int nf = 0; nf < 4; nf++) {
          int col = wn * 64 + nf * 16 + lm;
          float bv = (epi >= 1 && bias) ? bias[n0 + col] : 0.0f;
#pragma unroll
          for (int mf = 0; mf < 8; mf++)
#pragma unroll
            for (int r = 0; r < 4; r++) {
              float vv = acc[mf][nf][r] + bv;
              if (epi == 2) vv = gelu_f(vv);
              fs[(mf * 16 + quad * 4 + r) * 264 + col] = f2bf(vv);
            }
        }
      }
      __syncthreads();
#pragma unroll
      for (int p2 = 0; p2 < 8; p2++) {             // 128 rows x 32 uint4 chunks = 4096
        int idx = p2 * 512 + tid;
        int lrow = idx >> 5, c8 = idx & 31;
        int grow = remap_row(m0 + h * 128 + lrow, remap);
        *(uint4*)(outB + (long)grow * Nc + n0 + c8 * 8) = *(const uint4*)&fs[lrow * 264 + c8 * 8];
      }
    }
  }
}

// ---- spatial attention, HEAD-LOOP: one block per (b,t) frame, 8 heads sequential. ----
__global__ __launch_bounds__(384) void k_sp_attn(const u16* __restrict__ QKV, const u16* __restrict__ adj,
                                                 u16* __restrict__ O) {
  __shared__ __align__(16) u16 Qs[96 * 32];
  __shared__ __align__(16) u16 Ks[96 * 32];
  __shared__ __align__(16) u16 Vt[32 * 104];   // V^T: [dim][token], stride 104
  __shared__ __align__(16) u16 Ss[96 * 104];   // adj then P, stride 104
  int blk = blockIdx.x;
  blk = (blk & 7) * ((int)gridDim.x >> 3) + (blk >> 3);  // XCD-chunked (768 % 8 == 0)
  int t = blk % TT, b = blk / TT;
  long fQ = ((long)(b * TT + t) * EE) * 768;
  long fO = ((long)(b * TT + t) * EE) * CC;
  int tid = threadIdx.x;
  int row = tid >> 2, seg = tid & 3;
  int wv = tid >> 6, lane = tid & 63, lm = lane & 15, quad = lane >> 4;
  long gq0 = fQ + (long)row * 768 + seg * 8;
  uint4 rq = *(const uint4*)(QKV + gq0);
  uint4 rk = *(const uint4*)(QKV + gq0 + 256);
  uint4 rv = *(const uint4*)(QKV + gq0 + 512);
  int cb = seg * 24;
  for (int h = 0; h < 8; ++h) {
    *(uint4*)&Qs[row * 32 + seg * 8] = rq;
    *(uint4*)&Ks[row * 32 + seg * 8] = rk;
    { union { uint4 u; u16 s[8]; } vv; vv.u = rv;
#pragma unroll
      for (int i = 0; i < 8; i++) Vt[(seg * 8 + i) * 104 + row] = vv.s[i]; }
#pragma unroll
    for (int i = 0; i < 3; i++)
      *(uint4*)&Ss[row * 104 + cb + i * 8] = *(const uint4*)(adj + row * 96 + cb + i * 8);
    __syncthreads();
    if (h < 7) {  // T14: prefetch next head's QKV under this head's compute
      long g = gq0 + (h + 1) * 32;
      rq = *(const uint4*)(QKV + g);
      rk = *(const uint4*)(QKV + g + 256);
      rv = *(const uint4*)(QKV + g + 512);
      __builtin_amdgcn_sched_barrier(0);
    }
    bf16x8 aq = *(const bf16x8*)&Qs[(wv * 16 + lm) * 32 + quad * 8];
    f32x4 sc[6];
#pragma unroll
    for (int j = 0; j < 6; j++) {
      bf16x8 bk = *(const bf16x8*)&Ks[(j * 16 + lm) * 32 + quad * 8];
      f32x4 z = (f32x4){0.f, 0.f, 0.f, 0.f};
      sc[j] = __builtin_amdgcn_mfma_f32_16x16x32_bf16(aq, bk, z, 0, 0, 0);
    }
    u16 sv[6][4];
#pragma unroll
    for (int j = 0; j < 6; j++) {
      int col = j * 16 + lm;
#pragma unroll
      for (int r = 0; r < 4; r++) {
        int rrow = wv * 16 + quad * 4 + r;
        float a = bf2f(Ss[rrow * 104 + col]);
        sv[j][r] = f2bf((sc[j][r] * a + 1.0f) * 0.5f);
      }
    }
    __syncthreads();
#pragma unroll
    for (int j = 0; j < 6; j++) {
      int col = j * 16 + lm;
#pragma unroll
      for (int r = 0; r < 4; r++) Ss[(wv * 16 + quad * 4 + r) * 104 + col] = sv[j][r];
    }
    __syncthreads();
    f32x4 oc[2];
    oc[0] = (f32x4){0.f, 0.f, 0.f, 0.f};
    oc[1] = (f32x4){0.f, 0.f, 0.f, 0.f};
#pragma unroll
    for (int ks = 0; ks < 3; ks++) {
      bf16x8 as = *(const bf16x8*)&Ss[(wv * 16 + lm) * 104 + ks * 32 + quad * 8];
#pragma unroll
      for (int n = 0; n < 2; n++) {
        bf16x8 bv = *(const bf16x8*)&Vt[(n * 16 + lm) * 104 + ks * 32 + quad * 8];
        oc[n] = __builtin_amdgcn_mfma_f32_16x16x32_bf16(as, bv, oc[n], 0, 0, 0);
      }
    }
#pragma unroll
    for (int n = 0; n < 2; n++)
#pragma unroll
      for (int r = 0; r < 4; r++) {
        int rrow = wv * 16 + quad * 4 + r;
        O[fO + (long)rrow * CC + h * DDm + n * 16 + lm] = f2bf(oc[n][r]);
      }
    __syncthreads();
  }
}

// ---- temporal attention, HEAD-LOOP: one block per (b,e); register softmax per head. ----
__global__ __launch_bounds__(384) void k_tp_attn(const u16* __restrict__ QKV, u16* __restrict__ O) {
  __shared__ __align__(16) u16 Qs[96 * 32];
  __shared__ __align__(16) u16 Ks[96 * 32];
  __shared__ __align__(16) u16 Vt[32 * 104];   // V^T: [dim][token]
  __shared__ __align__(16) u16 Ss[96 * 104];   // P in bf16, stride 104
  int blk = blockIdx.x;
  blk = (blk & 7) * ((int)gridDim.x >> 3) + (blk >> 3);  // XCD-chunked
  int e = blk % EE, b = blk / EE;
  long fQ = ((long)(b * EE + e) * TT) * 768;
  long fO = ((long)(b * EE + e) * TT) * CC;
  int tid = threadIdx.x;
  int row = tid >> 2, seg = tid & 3;
  int wv = tid >> 6, lane = tid & 63, lm = lane & 15, quad = lane >> 4;
  long gq0 = fQ + (long)row * 768 + seg * 8;
  uint4 rq = *(const uint4*)(QKV + gq0);
  uint4 rk = *(const uint4*)(QKV + gq0 + 256);
  uint4 rv = *(const uint4*)(QKV + gq0 + 512);
  const float scale = 0.17677669529663687f;  // 1/sqrt(32)
  for (int h = 0; h < 8; ++h) {
    *(uint4*)&Qs[row * 32 + seg * 8] = rq;
    *(uint4*)&Ks[row * 32 + seg * 8] = rk;
    { union { uint4 u; u16 s[8]; } vv; vv.u = rv;
#pragma unroll
      for (int i = 0; i < 8; i++) Vt[(seg * 8 + i) * 104 + row] = vv.s[i]; }
    __syncthreads();
    if (h < 7) {
      long g = gq0 + (h + 1) * 32;
      rq = *(const uint4*)(QKV + g);
      rk = *(const uint4*)(QKV + g + 256);
      rv = *(const uint4*)(QKV + g + 512);
      __builtin_amdgcn_sched_barrier(0);
    }
    bf16x8 aq = *(const bf16x8*)&Qs[(wv * 16 + lm) * 32 + quad * 8];
    f32x4 sc[6];
#pragma unroll
    for (int j = 0; j < 6; j++) {
      bf16x8 bk = *(const bf16x8*)&Ks[(j * 16 + lm) * 32 + quad * 8];
      f32x4 z = (f32x4){0.f, 0.f, 0.f, 0.f};
      sc[j] = __builtin_amdgcn_mfma_f32_16x16x32_bf16(aq, bk, z, 0, 0, 0);
    }
#pragma unroll
    for (int r = 0; r < 4; r++) {
      float mx = -1e30f;
#pragma unroll
      for (int j = 0; j < 6; j++) { sc[j][r] *= scale; mx = fmaxf(mx, sc[j][r]); }
#pragma unroll
      for (int mask = 1; mask < 16; mask <<= 1) mx = fmaxf(mx, __shfl_xor(mx, mask));
      float sum = 0.f;
#pragma unroll
      for (int j = 0; j < 6; j++) { float p = __expf(sc[j][r] - mx); sc[j][r] = p; sum += p; }
#pragma unroll
      for (int mask = 1; mask < 16; mask <<= 1) sum += __shfl_xor(sum, mask);
      float inv = 1.0f / sum;
#pragma unroll
      for (int j = 0; j < 6; j++) sc[j][r] *= inv;
    }
#pragma unroll
    for (int j = 0; j < 6; j++) {
      int col = j * 16 + lm;
#pragma unroll
      for (int r = 0; r < 4; r++) Ss[(wv * 16 + quad * 4 + r) * 104 + col] = f2bf(sc[j][r]);
    }
    __syncthreads();
    f32x4 oc[2];
    oc[0] = (f32x4){0.f, 0.f, 0.f, 0.f};
    oc[1] = (f32x4){0.f, 0.f, 0.f, 0.f};
#pragma unroll
    for (int ks = 0; ks < 3; ks++) {
      bf16x8 as = *(const bf16x8*)&Ss[(wv * 16 + lm) * 104 + ks * 32 + quad * 8];
#pragma unroll
      for (int n = 0; n < 2; n++) {
        bf16x8 bv = *(const bf16x8*)&Vt[(n * 16 + lm) * 104 + ks * 32 + quad * 8];
        oc[n] = __builtin_amdgcn_mfma_f32_16x16x32_bf16(as, bv, oc[n], 0, 0, 0);
      }
    }
#pragma unroll
    for (int n = 0; n < 2; n++)
#pragma unroll
      for (int r = 0; r < 4; r++) {
        int rrow = wv * 16 + quad * 4 + r;  // t index
        O[fO + (long)rrow * CC + h * DDm + n * 16 + lm] = f2bf(oc[n][r]);
      }
    __syncthreads();
  }
}

// ------- downsample: out[b,i,e,c] = 0.5*(X[b,2i,e,c] + X[b,2i+1,e,c])  (fp32 out) -------
__global__ __launch_bounds__(256) void k_down(const float* __restrict__ X, float* __restrict__ out) {
  long i4 = ((long)blockIdx.x * 256 + threadIdx.x) * 4;
  long tmp = i4;
  int c = (int)(tmp & 255); tmp >>= 8;
  int e = (int)(tmp % EE); tmp /= EE;
  int i = (int)(tmp % TOUT);
  int b = (int)(tmp / TOUT);
  long src0 = (((long)b * TT + 2 * i) * EE + e) * CC + c;
  float4 a = *(const float4*)(X + src0);
  float4 bb = *(const float4*)(X + src0 + (long)EE * CC);
  float4 o = make_float4(0.5f * (a.x + bb.x), 0.5f * (a.y + bb.y),
                         0.5f * (a.z + bb.z), 0.5f * (a.w + bb.w));
  *(float4*)(out + i4) = o;
}

extern "C" void kernel_launch(void* const* d_in, const int* in_sizes, int n_in,
                              void* d_out, int out_size, void* d_ws, size_t ws_size,
                              hipStream_t stream) {
  (void)in_sizes; (void)n_in; (void)out_size; (void)ws_size;
  const float* x   = (const float*)d_in[0];
  const float* adj = (const float*)d_in[1];
  const float* n1g = (const float*)d_in[2];
  const float* n1b = (const float*)d_in[3];
  const float* swq = (const float*)d_in[4];
  const float* swk = (const float*)d_in[5];
  const float* swv = (const float*)d_in[6];
  const float* swp = (const float*)d_in[7];
  const float* sbp = (const float*)d_in[8];
  const float* sng = (const float*)d_in[9];
  const float* snb = (const float*)d_in[10];
  const float* sg  = (const float*)d_in[11];
  const float* n2g = (const float*)d_in[12];
  const float* n2b = (const float*)d_in[13];
  const float* twq = (const float*)d_in[14];
  const float* twk = (const float*)d_in[15];
  const float* twv = (const float*)d_in[16];
  const float* twp = (const float*)d_in[17];
  const float* tbp = (const float*)d_in[18];
  const float* tg  = (const float*)d_in[19];
  const float* n3g = (const float*)d_in[20];
  const float* n3b = (const float*)d_in[21];
  const float* mw1 = (const float*)d_in[22];
  const float* mb1 = (const float*)d_in[23];
  const float* mw2 = (const float*)d_in[24];
  const float* mb2 = (const float*)d_in[25];
  float* out = (float*)d_out;

  // ---- workspace: X fp32 | A bf16 | QKV bf16 [N,768] | weights ----
  size_t nc = (size_t)NTOK * CC;
  float* X  = (float*)d_ws;
  u16* A    = (u16*)(X + nc);
  u16* QKV  = A + nc;
  u16* Pb   = QKV;
  u16* Hh   = QKV;    // MLP: [N/2, 1024] = 75.5 MB fits in QKV (113 MB)
  u16* wts  = QKV + 3 * nc;
  u16* swq_t = wts;
  u16* swp_t = wts + 3 * 65536;
  u16* twq_t = wts + 4 * 65536;
  u16* twp_t = wts + 7 * 65536;
  u16* w1_t  = wts + 8 * 65536;  // [1024,256]
  u16* w2_t  = w1_t + 262144;    // [256,1024]
  u16* adj_b = w2_t + 262144;    // [96,96]

  WPtr8 w8; w8.p[0] = swq; w8.p[1] = swk; w8.p[2] = swv; w8.p[3] = swp;
  w8.p[4] = twq; w8.p[5] = twk; w8.p[6] = twv; w8.p[7] = twp;
  k_transpose8<<<dim3(256, 8), 256, 0, stream>>>(w8, wts);
  k_transpose<<<(256 * 1024 + 255) / 256, 256, 0, stream>>>(mw1, w1_t, 256, 1024, 256 * 1024);
  k_transpose<<<(1024 * 256 + 255) / 256, 256, 0, stream>>>(mw2, w2_t, 1024, 256, 1024 * 256);
  k_cvt<<<(EE * EE + 255) / 256, 256, 0, stream>>>(adj, adj_b, EE * EE);

  auto gemm = [&](const u16* act, const u16* Wt, const float* bias, const float* gamma,
                  u16* outB, float* Xacc, int Kd, int Nc, int lda, int ldb, int epi, int remap, int M) {
    dim3 g(Nc / 256, M / 256);
    k_gemm256<<<g, 512, 0, stream>>>(act, Wt, bias, gamma, outB, Xacc, Kd, Nc, lda, ldb, epi, remap);
  };

  int lnBlocks = NTOK / 4;

  // ---- spatial block ----
  k_ln_in<<<lnBlocks, 256, 0, stream>>>(x, A, n1g, n1b);                          // A = xs
  gemm(A, swq_t, nullptr, nullptr, QKV, nullptr, 256, 768, 256, 256, 0, 0, NTOK); // fused QKV (grid 3x288)
  k_sp_attn<<<BB * TT, 384, 0, stream>>>(QKV, adj_b, A);                          // O -> A (head loop)
  gemm(A, swp_t, sbp, nullptr, Pb, nullptr, 256, 256, 256, 256, 1, 0, NTOK);      // P -> Pb (grid 1x288)
  k_sp_combine<<<lnBlocks, 256, 0, stream>>>(x, X, A, Pb, n1g, n1b, sg, sng, snb, n2g, n2b);

  // ---- temporal block (token order [b,e,t] inside) ----
  gemm(A, twq_t, nullptr, nullptr, QKV, nullptr, 256, 768, 256, 256, 0, 1, NTOK); // fused QKV, bte->bet
  k_tp_attn<<<BB * EE, 384, 0, stream>>>(QKV, A);                                 // O -> A (bet, head loop)
  gemm(A, twp_t, tbp, tg, nullptr, X, 256, 256, 256, 256, 3, 2, NTOK);            // X += g*(O@wp+b), bet->bte

  // ---- MLP: token-split halves, full HID=1024 each (X RMW once per token) ----
  k_ln_f32<<<lnBlocks, 256, 0, stream>>>(X, A, n3g, n3b);                         // A = xm
  for (int hf = 0; hf < 2; hf++) {
    long r0 = (long)hf * (NTOK / 2);
    gemm(A + r0 * CC, w1_t, mb1, nullptr, Hh, nullptr, 256, 1024, 256, 256, 2, 0, NTOK / 2);   // 4x144
    gemm(Hh, w2_t, mb2, nullptr, nullptr, X + r0 * CC, 1024, 256, 1024, 1024, 3, 0, NTOK / 2); // 1x144
  }

  // ---- downsample (fp32 out) ----
  long outElems = (long)BB * TOUT * EE * CC;
  k_down<<<(int)(outElems / 4 / 256), 256, 0, stream>>>(X, out);
}

// Round 8
// 706.792 us; speedup vs baseline: 1.5664x; 1.5664x over previous
//
#include <hip/hip_runtime.h>
#include <cmath>

constexpr int BB = 8, TT = 96, EE = 96, CC = 256, HHD = 8, DDm = 32;
constexpr int NTOK = BB * TT * EE;   // 73728
constexpr int TOUT = TT / 2;         // 48

typedef unsigned short u16;
typedef short bf16x8 __attribute__((ext_vector_type(8)));
typedef float f32x4 __attribute__((ext_vector_type(4)));

__device__ __forceinline__ float bf2f(u16 u) {
  union { unsigned int i; float f; } v; v.i = ((unsigned int)u) << 16; return v.f;
}
__device__ __forceinline__ u16 f2bf(float f) {
  union { unsigned int i; float f; } v; v.f = f;
  return (u16)((v.i + 0x7FFFu + ((v.i >> 16) & 1u)) >> 16);  // RNE
}
__device__ __forceinline__ float wsum(float v) {
#pragma unroll
  for (int off = 32; off; off >>= 1) v += __shfl_xor(v, off);
  return v;
}
__device__ __forceinline__ float gelu_f(float x) {
  return 0.5f * x * (1.0f + erff(x * 0.70710678118654752f));
}
// token-order permutations: 0=id, 1=[b,t,e]->[b,e,t] position, 2=[b,e,t]->[b,t,e]
__device__ __forceinline__ int remap_row(int row, int mode) {
  if (mode == 0) return row;
  int b = row / (TT * EE);
  int rem = row - b * (TT * EE);
  if (mode == 1) { int t = rem / EE, e = rem - t * EE; return (b * EE + e) * TT + t; }
  int e = rem / TT, t = rem - e * TT;
  return (b * TT + t) * EE + e;
}

// -------- batched weight transpose+convert: 8 x [256,256] fp32 -> bf16 [Nc][K] --------
struct WPtr8 { const float* p[8]; };
__global__ void k_transpose8(WPtr8 src, u16* __restrict__ dst) {
  const float* in = src.p[blockIdx.y];
  u16* out = dst + (size_t)blockIdx.y * 65536;
  int idx = blockIdx.x * 256 + threadIdx.x;
  int k = idx >> 8, c = idx & 255;
  out[c * 256 + k] = f2bf(in[idx]);
}

// -------- weight transpose+convert: W fp32 [K][Nc] -> Wt bf16 [Nc][K] --------
__global__ void k_transpose(const float* __restrict__ in, u16* __restrict__ out, int K, int Nc, int n) {
  int idx = blockIdx.x * 256 + threadIdx.x;
  if (idx < n) {
    int k = idx / Nc, c = idx - k * Nc;
    out[c * K + k] = f2bf(in[idx]);
  }
}

// -------- fp32 -> bf16 convert (adj) --------
__global__ void k_cvt(const float* __restrict__ in, u16* __restrict__ out, int n) {
  int idx = blockIdx.x * 256 + threadIdx.x;
  if (idx < n) out[idx] = f2bf(in[idx]);
}

// ------- LN of fp32 input x -> A = LN(x)*g+b (bf16); no X copy -------
__global__ __launch_bounds__(256) void k_ln_in(const float* __restrict__ x,
                                               u16* __restrict__ A, const float* __restrict__ g,
                                               const float* __restrict__ b) {
  int wv = threadIdx.x >> 6, lane = threadIdx.x & 63;
  long tok = (long)blockIdx.x * 4 + wv;
  int c = lane * 4;
  long off = tok * CC + c;
  float4 v = *(const float4*)(x + off);
  float s = v.x + v.y + v.z + v.w;
  float sq = v.x * v.x + v.y * v.y + v.z * v.z + v.w * v.w;
  s = wsum(s); sq = wsum(sq);
  float m = s * (1.0f / CC);
  float rs = rsqrtf(sq * (1.0f / CC) - m * m + 1e-5f);
  float4 gv = *(const float4*)(g + c);
  float4 bv = *(const float4*)(b + c);
  ushort4 o;
  o.x = f2bf((v.x - m) * rs * gv.x + bv.x);
  o.y = f2bf((v.y - m) * rs * gv.y + bv.y);
  o.z = f2bf((v.z - m) * rs * gv.z + bv.z);
  o.w = f2bf((v.w - m) * rs * gv.w + bv.w);
  *(ushort4*)(A + off) = o;
}

// ---------------- A = LN(X fp32)*g+b ----------------
__global__ __launch_bounds__(256) void k_ln_f32(const float* __restrict__ X, u16* __restrict__ A,
                                                const float* __restrict__ g, const float* __restrict__ b) {
  int wv = threadIdx.x >> 6, lane = threadIdx.x & 63;
  long tok = (long)blockIdx.x * 4 + wv;
  int c = lane * 4;
  long off = tok * CC + c;
  float4 v = *(const float4*)(X + off);
  float s = v.x + v.y + v.z + v.w;
  float sq = v.x * v.x + v.y * v.y + v.z * v.z + v.w * v.w;
  s = wsum(s); sq = wsum(sq);
  float m = s * (1.0f / CC);
  float rs = rsqrtf(sq * (1.0f / CC) - m * m + 1e-5f);
  float4 gv = *(const float4*)(g + c);
  float4 bv = *(const float4*)(b + c);
  ushort4 o;
  o.x = f2bf((v.x - m) * rs * gv.x + bv.x);
  o.y = f2bf((v.y - m) * rs * gv.y + bv.y);
  o.z = f2bf((v.z - m) * rs * gv.z + bv.z);
  o.w = f2bf((v.w - m) * rs * gv.w + bv.w);
  *(ushort4*)(A + off) = o;
}

// ------- spatial combine: reads pristine x; xs = LN1(x); o = LN(P)*s_ng+s_nb;
//         X = x + xs + s_gamma*o (first write of X); A = LN2(X) -------
__global__ __launch_bounds__(256) void k_sp_combine(const float* __restrict__ xin, float* __restrict__ X,
                                                    u16* __restrict__ A, const u16* __restrict__ P,
                                                    const float* __restrict__ n1g, const float* __restrict__ n1b,
                                                    const float* __restrict__ sg,
                                                    const float* __restrict__ s_ng, const float* __restrict__ s_nb,
                                                    const float* __restrict__ n2g, const float* __restrict__ n2b) {
  int wv = threadIdx.x >> 6, lane = threadIdx.x & 63;
  long tok = (long)blockIdx.x * 4 + wv;
  int c = lane * 4;
  long off = tok * CC + c;
  float4 xv = *(const float4*)(xin + off);
  float s1 = xv.x + xv.y + xv.z + xv.w;
  float q1 = xv.x * xv.x + xv.y * xv.y + xv.z * xv.z + xv.w * xv.w;
  s1 = wsum(s1); q1 = wsum(q1);
  float m1 = s1 * (1.0f / CC);
  float r1 = rsqrtf(q1 * (1.0f / CC) - m1 * m1 + 1e-5f);
  float4 g1 = *(const float4*)(n1g + c);
  float4 b1 = *(const float4*)(n1b + c);
  float xs0 = (xv.x - m1) * r1 * g1.x + b1.x;
  float xs1 = (xv.y - m1) * r1 * g1.y + b1.y;
  float xs2 = (xv.z - m1) * r1 * g1.z + b1.z;
  float xs3 = (xv.w - m1) * r1 * g1.w + b1.w;
  ushort4 up = *(const ushort4*)(P + off);
  float4 p = make_float4(bf2f(up.x), bf2f(up.y), bf2f(up.z), bf2f(up.w));
  float s = p.x + p.y + p.z + p.w;
  float sq = p.x * p.x + p.y * p.y + p.z * p.z + p.w * p.w;
  s = wsum(s); sq = wsum(sq);
  float m = s * (1.0f / CC);
  float rs = rsqrtf(sq * (1.0f / CC) - m * m + 1e-5f);
  float4 ug = *(const float4*)(s_ng + c);
  float4 ub = *(const float4*)(s_nb + c);
  float o0 = (p.x - m) * rs * ug.x + ub.x;
  float o1 = (p.y - m) * rs * ug.y + ub.y;
  float o2 = (p.z - m) * rs * ug.z + ub.z;
  float o3 = (p.w - m) * rs * ug.w + ub.w;
  float gsg = sg[0];
  float x0 = xv.x + xs0 + gsg * o0;
  float x1 = xv.y + xs1 + gsg * o1;
  float x2 = xv.z + xs2 + gsg * o2;
  float x3 = xv.w + xs3 + gsg * o3;
  *(float4*)(X + off) = make_float4(x0, x1, x2, x3);
  float s2 = x0 + x1 + x2 + x3;
  float sq2 = x0 * x0 + x1 * x1 + x2 * x2 + x3 * x3;
  s2 = wsum(s2); sq2 = wsum(sq2);
  float m2 = s2 * (1.0f / CC);
  float rs2 = rsqrtf(sq2 * (1.0f / CC) - m2 * m2 + 1e-5f);
  float4 g2 = *(const float4*)(n2g + c);
  float4 b2 = *(const float4*)(n2b + c);
  ushort4 o;
  o.x = f2bf((x0 - m2) * rs2 * g2.x + b2.x);
  o.y = f2bf((x1 - m2) * rs2 * g2.y + b2.y);
  o.z = f2bf((x2 - m2) * rs2 * g2.z + b2.z);
  o.w = f2bf((x3 - m2) * rs2 * g2.w + b2.w);
  *(ushort4*)(A + off) = o;
}

// ---- 128x128-tile MFMA GEMM: out[M,Nc] = act[M,Kd](lda) @ Wt[Nc,Kd](ldb)^T ----
// ROUND-3 VERIFIED CONFIG (671 us, MfmaUtil 17.5%): BK=32, 3-buffer LDS (49KB, 3 blk/CU),
// depth-2 prefetch vmcnt(4), seg XOR-swizzle (rule-21 both-sides), setprio, sched_barrier guards.
// Round-4 BK=64 (2 blk/CU) and round-7 256x256/8-wave lockstep (1 blk/CU, MfmaUtil 7.4%) both
// REGRESSED: in this regime block-level TLP beats per-barrier MFMA density. Do not enlarge LDS.
__global__ __launch_bounds__(256) void k_gemm128(const u16* __restrict__ act, const u16* __restrict__ Wt,
                                                 const float* __restrict__ bias, const float* __restrict__ gptr,
                                                 u16* __restrict__ outB, float* __restrict__ Xacc,
                                                 int Kd, int Nc, int lda, int ldb, int epi, int remap) {
  __shared__ __align__(16) u16 smem[3 * 8192];   // 49152 B: 3 x (As 4096 + Bs 4096); epilogue aliases
  int gx = gridDim.x;
  int nwg = gx * gridDim.y;
  int lid = blockIdx.y * gx + blockIdx.x;
  if ((nwg & 7) == 0) lid = (lid & 7) * (nwg >> 3) + (lid >> 3);  // XCD-chunked (bijective: nwg%8==0)
  int m0 = (lid / gx) * 128, n0 = (lid % gx) * 128;
  int tid = threadIdx.x;
  int wv = tid >> 6, lane = tid & 63, lm = lane & 15, quad = lane >> 4;
  int wr = wv >> 1, wc = wv & 1;
  f32x4 acc[4][4];
#pragma unroll
  for (int i = 0; i < 4; i++)
#pragma unroll
    for (int j = 0; j < 4; j++) acc[i][j] = (f32x4){0.f, 0.f, 0.f, 0.f};

  int srow = tid >> 2;
  int sseg = (tid & 3) ^ ((srow >> 1) & 3);
  const u16* pa = act + (long)(m0 + srow) * lda + sseg * 8;
  const u16* pb = Wt + (long)(n0 + srow) * ldb + sseg * 8;

  auto STAGE = [&](int buf, int kk) {
    u16* sb = smem + buf * 8192;  // [As | Bs] per buffer, 4096 u16 each
#pragma unroll
    for (int j = 0; j < 2; j++) {
      __builtin_amdgcn_global_load_lds(pa + (long)j * 64 * lda + kk, sb + (j * 256 + wv * 64) * 8, 16, 0, 0);
      __builtin_amdgcn_global_load_lds(pb + (long)j * 64 * ldb + kk, sb + 4096 + (j * 256 + wv * 64) * 8, 16, 0, 0);
    }
  };

  int nsteps = Kd >> 5;              // always >= 8 here
  STAGE(0, 0);
  STAGE(1, 32);
  asm volatile("s_waitcnt vmcnt(4)" ::: "memory");   // tile0 landed; tile1 in flight
  __builtin_amdgcn_sched_barrier(0);
  __builtin_amdgcn_s_barrier();

  int xsw = (lm >> 1) & 3;           // read-side swizzle: slot = quad ^ xsw (involution of source swizzle)
  int cur = 0;
  for (int t = 0; t < nsteps; ++t) {
    if (t + 2 < nsteps) {
      int nb = cur + 2; if (nb >= 3) nb -= 3;
      STAGE(nb, (t + 2) << 5);       // depth-2 prefetch
    }
    const u16* As = smem + cur * 8192;
    const u16* Bs = As + 4096;
    bf16x8 af[4], bfv[4];
#pragma unroll
    for (int q = 0; q < 4; q++) {
      af[q] = *(const bf16x8*)&As[(wr * 64 + q * 16 + lm) * 32 + (quad ^ xsw) * 8];
      bfv[q] = *(const bf16x8*)&Bs[(wc * 64 + q * 16 + lm) * 32 + (quad ^ xsw) * 8];
    }
    __builtin_amdgcn_s_setprio(1);
#pragma unroll
    for (int ti = 0; ti < 4; ti++)
#pragma unroll
      for (int tj = 0; tj < 4; tj++)
        acc[ti][tj] = __builtin_amdgcn_mfma_f32_16x16x32_bf16(af[ti], bfv[tj], acc[ti][tj], 0, 0, 0);
    __builtin_amdgcn_s_setprio(0);
    asm volatile("s_waitcnt lgkmcnt(0)" ::: "memory");          // my ds_reads done -> buf reusable
    __builtin_amdgcn_sched_barrier(0);
    if (t + 2 < nsteps) asm volatile("s_waitcnt vmcnt(4)" ::: "memory");  // tile t+1 landed (t+2 stays in flight)
    else                asm volatile("s_waitcnt vmcnt(0)" ::: "memory");  // drain tail
    __builtin_amdgcn_sched_barrier(0);
    __builtin_amdgcn_s_barrier();
    cur += 1; if (cur >= 3) cur -= 3;
  }

  if (epi == 3) {
    float gm = gptr ? gptr[0] : 1.0f;
    float* fs = (float*)smem;  // 64 x 132 fp32 = 33792 B
#pragma unroll
    for (int half = 0; half < 2; half++) {
      if (half) __syncthreads();
      if (wr == half) {
#pragma unroll
        for (int tj = 0; tj < 4; tj++) {
          int col = wc * 64 + tj * 16 + lm;
          float bv = bias ? bias[n0 + col] : 0.0f;
#pragma unroll
          for (int ti = 0; ti < 4; ti++)
#pragma unroll
            for (int r = 0; r < 4; r++)
              fs[(ti * 16 + quad * 4 + r) * 132 + col] = gm * (acc[ti][tj][r] + bv);
        }
      }
      __syncthreads();
      // coalesced float4 RMW of 64 rows x 128 cols
#pragma unroll
      for (int p = 0; p < 8; p++) {
        int idx = p * 256 + tid;            // 2048 float4 chunks
        int row = idx >> 5, c4 = idx & 31;
        int grow = remap_row(m0 + half * 64 + row, remap);
        float* gp = Xacc + (long)grow * Nc + n0 + c4 * 4;
        float4 xv = *(float4*)gp;
        float4 sv = *(const float4*)&fs[row * 132 + c4 * 4];
        xv.x += sv.x; xv.y += sv.y; xv.z += sv.z; xv.w += sv.w;
        *(float4*)gp = xv;
      }
    }
  } else {
    // stage C in LDS (row stride 136 u16 de-conflicts banks), then coalesced uint4 writes
#pragma unroll
    for (int tj = 0; tj < 4; tj++) {
      int col = wc * 64 + tj * 16 + lm;
      float bv = (epi >= 1 && bias) ? bias[n0 + col] : 0.0f;
#pragma unroll
      for (int ti = 0; ti < 4; ti++)
#pragma unroll
        for (int r = 0; r < 4; r++) {
          float vv = acc[ti][tj][r] + bv;
          if (epi == 2) vv = gelu_f(vv);
          smem[(wr * 64 + ti * 16 + quad * 4 + r) * 136 + col] = f2bf(vv);
        }
    }
    __syncthreads();
#pragma unroll
    for (int p = 0; p < 8; p++) {
      int idx = p * 256 + tid;             // 2048 uint4 chunks of the 128x128 tile
      int row = idx >> 4, c8 = idx & 15;
      int grow = remap_row(m0 + row, remap);
      *(uint4*)(outB + (long)grow * Nc + n0 + c8 * 8) = *(const uint4*)&smem[row * 136 + c8 * 8];
    }
  }
}

// ---- spatial attention, HEAD-LOOP: one block per (b,t) frame, 8 heads sequential. ----
// Grid 768 (1 round at 3 blk/CU, zero tail). Head h+1's QKV prefetched into registers (T14)
// right after head h's staging barrier -> load latency hides under head h's MFMA+mask.
__global__ __launch_bounds__(384) void k_sp_attn(const u16* __restrict__ QKV, const u16* __restrict__ adj,
                                                 u16* __restrict__ O) {
  __shared__ __align__(16) u16 Qs[96 * 32];
  __shared__ __align__(16) u16 Ks[96 * 32];
  __shared__ __align__(16) u16 Vt[32 * 104];   // V^T: [dim][token], stride 104
  __shared__ __align__(16) u16 Ss[96 * 104];   // adj then P, stride 104
  int blk = blockIdx.x;
  blk = (blk & 7) * ((int)gridDim.x >> 3) + (blk >> 3);  // XCD-chunked (768 % 8 == 0)
  int t = blk % TT, b = blk / TT;
  long fQ = ((long)(b * TT + t) * EE) * 768;
  long fO = ((long)(b * TT + t) * EE) * CC;
  int tid = threadIdx.x;
  int row = tid >> 2, seg = tid & 3;
  int wv = tid >> 6, lane = tid & 63, lm = lane & 15, quad = lane >> 4;
  long gq0 = fQ + (long)row * 768 + seg * 8;
  uint4 rq = *(const uint4*)(QKV + gq0);
  uint4 rk = *(const uint4*)(QKV + gq0 + 256);
  uint4 rv = *(const uint4*)(QKV + gq0 + 512);
  int cb = seg * 24;
  for (int h = 0; h < 8; ++h) {
    *(uint4*)&Qs[row * 32 + seg * 8] = rq;
    *(uint4*)&Ks[row * 32 + seg * 8] = rk;
    { union { uint4 u; u16 s[8]; } vv; vv.u = rv;
#pragma unroll
      for (int i = 0; i < 8; i++) Vt[(seg * 8 + i) * 104 + row] = vv.s[i]; }
#pragma unroll
    for (int i = 0; i < 3; i++)
      *(uint4*)&Ss[row * 104 + cb + i * 8] = *(const uint4*)(adj + row * 96 + cb + i * 8);
    __syncthreads();
    if (h < 7) {  // T14: prefetch next head's QKV under this head's compute
      long g = gq0 + (h + 1) * 32;
      rq = *(const uint4*)(QKV + g);
      rk = *(const uint4*)(QKV + g + 256);
      rv = *(const uint4*)(QKV + g + 512);
      __builtin_amdgcn_sched_barrier(0);   // pin load issue here (don't sink to use)
    }
    bf16x8 aq = *(const bf16x8*)&Qs[(wv * 16 + lm) * 32 + quad * 8];
    f32x4 sc[6];
#pragma unroll
    for (int j = 0; j < 6; j++) {
      bf16x8 bk = *(const bf16x8*)&Ks[(j * 16 + lm) * 32 + quad * 8];
      f32x4 z = (f32x4){0.f, 0.f, 0.f, 0.f};
      sc[j] = __builtin_amdgcn_mfma_f32_16x16x32_bf16(aq, bk, z, 0, 0, 0);
    }
    u16 sv[6][4];
#pragma unroll
    for (int j = 0; j < 6; j++) {
      int col = j * 16 + lm;
#pragma unroll
      for (int r = 0; r < 4; r++) {
        int rrow = wv * 16 + quad * 4 + r;
        float a = bf2f(Ss[rrow * 104 + col]);
        sv[j][r] = f2bf((sc[j][r] * a + 1.0f) * 0.5f);
      }
    }
    __syncthreads();
#pragma unroll
    for (int j = 0; j < 6; j++) {
      int col = j * 16 + lm;
#pragma unroll
      for (int r = 0; r < 4; r++) Ss[(wv * 16 + quad * 4 + r) * 104 + col] = sv[j][r];
    }
    __syncthreads();
    f32x4 oc[2];
    oc[0] = (f32x4){0.f, 0.f, 0.f, 0.f};
    oc[1] = (f32x4){0.f, 0.f, 0.f, 0.f};
#pragma unroll
    for (int ks = 0; ks < 3; ks++) {
      bf16x8 as = *(const bf16x8*)&Ss[(wv * 16 + lm) * 104 + ks * 32 + quad * 8];
#pragma unroll
      for (int n = 0; n < 2; n++) {
        bf16x8 bv = *(const bf16x8*)&Vt[(n * 16 + lm) * 104 + ks * 32 + quad * 8];
        oc[n] = __builtin_amdgcn_mfma_f32_16x16x32_bf16(as, bv, oc[n], 0, 0, 0);
      }
    }
#pragma unroll
    for (int n = 0; n < 2; n++)
#pragma unroll
      for (int r = 0; r < 4; r++) {
        int rrow = wv * 16 + quad * 4 + r;
        O[fO + (long)rrow * CC + h * DDm + n * 16 + lm] = f2bf(oc[n][r]);
      }
    __syncthreads();
  }
}

// ---- temporal attention, HEAD-LOOP: one block per (b,e); register softmax per head. ----
__global__ __launch_bounds__(384) void k_tp_attn(const u16* __restrict__ QKV, u16* __restrict__ O) {
  __shared__ __align__(16) u16 Qs[96 * 32];
  __shared__ __align__(16) u16 Ks[96 * 32];
  __shared__ __align__(16) u16 Vt[32 * 104];   // V^T: [dim][token]
  __shared__ __align__(16) u16 Ss[96 * 104];   // P in bf16, stride 104
  int blk = blockIdx.x;
  blk = (blk & 7) * ((int)gridDim.x >> 3) + (blk >> 3);  // XCD-chunked
  int e = blk % EE, b = blk / EE;
  long fQ = ((long)(b * EE + e) * TT) * 768;
  long fO = ((long)(b * EE + e) * TT) * CC;
  int tid = threadIdx.x;
  int row = tid >> 2, seg = tid & 3;
  int wv = tid >> 6, lane = tid & 63, lm = lane & 15, quad = lane >> 4;
  long gq0 = fQ + (long)row * 768 + seg * 8;
  uint4 rq = *(const uint4*)(QKV + gq0);
  uint4 rk = *(const uint4*)(QKV + gq0 + 256);
  uint4 rv = *(const uint4*)(QKV + gq0 + 512);
  const float scale = 0.17677669529663687f;  // 1/sqrt(32)
  for (int h = 0; h < 8; ++h) {
    *(uint4*)&Qs[row * 32 + seg * 8] = rq;
    *(uint4*)&Ks[row * 32 + seg * 8] = rk;
    { union { uint4 u; u16 s[8]; } vv; vv.u = rv;
#pragma unroll
      for (int i = 0; i < 8; i++) Vt[(seg * 8 + i) * 104 + row] = vv.s[i]; }
    __syncthreads();
    if (h < 7) {
      long g = gq0 + (h + 1) * 32;
      rq = *(const uint4*)(QKV + g);
      rk = *(const uint4*)(QKV + g + 256);
      rv = *(const uint4*)(QKV + g + 512);
      __builtin_amdgcn_sched_barrier(0);
    }
    bf16x8 aq = *(const bf16x8*)&Qs[(wv * 16 + lm) * 32 + quad * 8];
    f32x4 sc[6];
#pragma unroll
    for (int j = 0; j < 6; j++) {
      bf16x8 bk = *(const bf16x8*)&Ks[(j * 16 + lm) * 32 + quad * 8];
      f32x4 z = (f32x4){0.f, 0.f, 0.f, 0.f};
      sc[j] = __builtin_amdgcn_mfma_f32_16x16x32_bf16(aq, bk, z, 0, 0, 0);
    }
#pragma unroll
    for (int r = 0; r < 4; r++) {
      float mx = -1e30f;
#pragma unroll
      for (int j = 0; j < 6; j++) { sc[j][r] *= scale; mx = fmaxf(mx, sc[j][r]); }
#pragma unroll
      for (int mask = 1; mask < 16; mask <<= 1) mx = fmaxf(mx, __shfl_xor(mx, mask));
      float sum = 0.f;
#pragma unroll
      for (int j = 0; j < 6; j++) { float p = __expf(sc[j][r] - mx); sc[j][r] = p; sum += p; }
#pragma unroll
      for (int mask = 1; mask < 16; mask <<= 1) sum += __shfl_xor(sum, mask);
      float inv = 1.0f / sum;
#pragma unroll
      for (int j = 0; j < 6; j++) sc[j][r] *= inv;
    }
#pragma unroll
    for (int j = 0; j < 6; j++) {
      int col = j * 16 + lm;
#pragma unroll
      for (int r = 0; r < 4; r++) Ss[(wv * 16 + quad * 4 + r) * 104 + col] = f2bf(sc[j][r]);
    }
    __syncthreads();
    f32x4 oc[2];
    oc[0] = (f32x4){0.f, 0.f, 0.f, 0.f};
    oc[1] = (f32x4){0.f, 0.f, 0.f, 0.f};
#pragma unroll
    for (int ks = 0; ks < 3; ks++) {
      bf16x8 as = *(const bf16x8*)&Ss[(wv * 16 + lm) * 104 + ks * 32 + quad * 8];
#pragma unroll
      for (int n = 0; n < 2; n++) {
        bf16x8 bv = *(const bf16x8*)&Vt[(n * 16 + lm) * 104 + ks * 32 + quad * 8];
        oc[n] = __builtin_amdgcn_mfma_f32_16x16x32_bf16(as, bv, oc[n], 0, 0, 0);
      }
    }
#pragma unroll
    for (int n = 0; n < 2; n++)
#pragma unroll
      for (int r = 0; r < 4; r++) {
        int rrow = wv * 16 + quad * 4 + r;  // t index
        O[fO + (long)rrow * CC + h * DDm + n * 16 + lm] = f2bf(oc[n][r]);
      }
    __syncthreads();
  }
}

// ------- downsample: out[b,i,e,c] = 0.5*(X[b,2i,e,c] + X[b,2i+1,e,c])  (fp32 out) -------
__global__ __launch_bounds__(256) void k_down(const float* __restrict__ X, float* __restrict__ out) {
  long i4 = ((long)blockIdx.x * 256 + threadIdx.x) * 4;
  long tmp = i4;
  int c = (int)(tmp & 255); tmp >>= 8;
  int e = (int)(tmp % EE); tmp /= EE;
  int i = (int)(tmp % TOUT);
  int b = (int)(tmp / TOUT);
  long src0 = (((long)b * TT + 2 * i) * EE + e) * CC + c;
  float4 a = *(const float4*)(X + src0);
  float4 bb = *(const float4*)(X + src0 + (long)EE * CC);
  float4 o = make_float4(0.5f * (a.x + bb.x), 0.5f * (a.y + bb.y),
                         0.5f * (a.z + bb.z), 0.5f * (a.w + bb.w));
  *(float4*)(out + i4) = o;
}

extern "C" void kernel_launch(void* const* d_in, const int* in_sizes, int n_in,
                              void* d_out, int out_size, void* d_ws, size_t ws_size,
                              hipStream_t stream) {
  (void)in_sizes; (void)n_in; (void)out_size; (void)ws_size;
  const float* x   = (const float*)d_in[0];
  const float* adj = (const float*)d_in[1];
  const float* n1g = (const float*)d_in[2];
  const float* n1b = (const float*)d_in[3];
  const float* swq = (const float*)d_in[4];
  const float* swk = (const float*)d_in[5];
  const float* swv = (const float*)d_in[6];
  const float* swp = (const float*)d_in[7];
  const float* sbp = (const float*)d_in[8];
  const float* sng = (const float*)d_in[9];
  const float* snb = (const float*)d_in[10];
  const float* sg  = (const float*)d_in[11];
  const float* n2g = (const float*)d_in[12];
  const float* n2b = (const float*)d_in[13];
  const float* twq = (const float*)d_in[14];
  const float* twk = (const float*)d_in[15];
  const float* twv = (const float*)d_in[16];
  const float* twp = (const float*)d_in[17];
  const float* tbp = (const float*)d_in[18];
  const float* tg  = (const float*)d_in[19];
  const float* n3g = (const float*)d_in[20];
  const float* n3b = (const float*)d_in[21];
  const float* mw1 = (const float*)d_in[22];
  const float* mb1 = (const float*)d_in[23];
  const float* mw2 = (const float*)d_in[24];
  const float* mb2 = (const float*)d_in[25];
  float* out = (float*)d_out;

  // ---- workspace: X fp32 | A bf16 | QKV bf16 [N,768] | weights ----
  size_t nc = (size_t)NTOK * CC;
  float* X  = (float*)d_ws;
  u16* A    = (u16*)(X + nc);
  u16* QKV  = A + nc;
  u16* Pb   = QKV;
  u16* Hh   = QKV;    // MLP: [N/2, 1024] = 75.5 MB fits in QKV (113 MB)
  u16* wts  = QKV + 3 * nc;
  u16* swq_t = wts;
  u16* swp_t = wts + 3 * 65536;
  u16* twq_t = wts + 4 * 65536;
  u16* twp_t = wts + 7 * 65536;
  u16* w1_t  = wts + 8 * 65536;  // [1024,256]
  u16* w2_t  = w1_t + 262144;    // [256,1024]
  u16* adj_b = w2_t + 262144;    // [96,96]

  WPtr8 w8; w8.p[0] = swq; w8.p[1] = swk; w8.p[2] = swv; w8.p[3] = swp;
  w8.p[4] = twq; w8.p[5] = twk; w8.p[6] = twv; w8.p[7] = twp;
  k_transpose8<<<dim3(256, 8), 256, 0, stream>>>(w8, wts);
  k_transpose<<<(256 * 1024 + 255) / 256, 256, 0, stream>>>(mw1, w1_t, 256, 1024, 256 * 1024);
  k_transpose<<<(1024 * 256 + 255) / 256, 256, 0, stream>>>(mw2, w2_t, 1024, 256, 1024 * 256);
  k_cvt<<<(EE * EE + 255) / 256, 256, 0, stream>>>(adj, adj_b, EE * EE);

  auto gemm = [&](const u16* act, const u16* Wt, const float* bias, const float* gamma,
                  u16* outB, float* Xacc, int Kd, int Nc, int lda, int ldb, int epi, int remap, int M) {
    dim3 g(Nc / 128, M / 128);
    k_gemm128<<<g, 256, 0, stream>>>(act, Wt, bias, gamma, outB, Xacc, Kd, Nc, lda, ldb, epi, remap);
  };

  int lnBlocks = NTOK / 4;

  // ---- spatial block ----
  k_ln_in<<<lnBlocks, 256, 0, stream>>>(x, A, n1g, n1b);                          // A = xs
  gemm(A, swq_t, nullptr, nullptr, QKV, nullptr, 256, 768, 256, 256, 0, 0, NTOK); // fused QKV
  k_sp_attn<<<BB * TT, 384, 0, stream>>>(QKV, adj_b, A);                          // O -> A (head loop)
  gemm(A, swp_t, sbp, nullptr, Pb, nullptr, 256, 256, 256, 256, 1, 0, NTOK);      // P -> Pb
  k_sp_combine<<<lnBlocks, 256, 0, stream>>>(x, X, A, Pb, n1g, n1b, sg, sng, snb, n2g, n2b);

  // ---- temporal block (token order [b,e,t] inside) ----
  gemm(A, twq_t, nullptr, nullptr, QKV, nullptr, 256, 768, 256, 256, 0, 1, NTOK); // fused QKV, bte->bet
  k_tp_attn<<<BB * EE, 384, 0, stream>>>(QKV, A);                                 // O -> A (bet, head loop)
  gemm(A, twp_t, tbp, tg, nullptr, X, 256, 256, 256, 256, 3, 2, NTOK);            // X += g*(O@wp+b), bet->bte

  // ---- MLP: token-split halves, full HID=1024 each (X RMW once per token) ----
  k_ln_f32<<<lnBlocks, 256, 0, stream>>>(X, A, n3g, n3b);                         // A = xm
  for (int hf = 0; hf < 2; hf++) {
    long r0 = (long)hf * (NTOK / 2);
    gemm(A + r0 * CC, w1_t, mb1, nullptr, Hh, nullptr, 256, 1024, 256, 256, 2, 0, NTOK / 2);
    gemm(Hh, w2_t, mb2, nullptr, nullptr, X + r0 * CC, 1024, 256, 1024, 1024, 3, 0, NTOK / 2);
  }

  // ---- downsample (fp32 out) ----
  long outElems = (long)BB * TOUT * EE * CC;
  k_down<<<(int)(outElems / 4 / 256), 256, 0, stream>>>(X, out);
}

// Round 9
// 688.338 us; speedup vs baseline: 1.6084x; 1.0268x over previous
//
#include <hip/hip_runtime.h>
#include <cmath>

constexpr int BB = 8, TT = 96, EE = 96, CC = 256, HHD = 8, DDm = 32;
constexpr int NTOK = BB * TT * EE;   // 73728
constexpr int TOUT = TT / 2;         // 48

typedef unsigned short u16;
typedef short bf16x8 __attribute__((ext_vector_type(8)));
typedef float f32x4 __attribute__((ext_vector_type(4)));

__device__ __forceinline__ float bf2f(u16 u) {
  union { unsigned int i; float f; } v; v.i = ((unsigned int)u) << 16; return v.f;
}
__device__ __forceinline__ u16 f2bf(float f) {
  union { unsigned int i; float f; } v; v.f = f;
  return (u16)((v.i + 0x7FFFu + ((v.i >> 16) & 1u)) >> 16);  // RNE
}
__device__ __forceinline__ float wsum(float v) {
#pragma unroll
  for (int off = 32; off; off >>= 1) v += __shfl_xor(v, off);
  return v;
}
__device__ __forceinline__ float gelu_f(float x) {
  return 0.5f * x * (1.0f + erff(x * 0.70710678118654752f));
}
// token-order permutations: 0=id, 1=[b,t,e]->[b,e,t] position, 2=[b,e,t]->[b,t,e]
__device__ __forceinline__ int remap_row(int row, int mode) {
  if (mode == 0) return row;
  int b = row / (TT * EE);
  int rem = row - b * (TT * EE);
  if (mode == 1) { int t = rem / EE, e = rem - t * EE; return (b * EE + e) * TT + t; }
  int e = rem / TT, t = rem - e * TT;
  return (b * TT + t) * EE + e;
}

// -------- batched weight transpose+convert: 8 x [256,256] fp32 -> bf16 [Nc][K] --------
struct WPtr8 { const float* p[8]; };
__global__ void k_transpose8(WPtr8 src, u16* __restrict__ dst) {
  const float* in = src.p[blockIdx.y];
  u16* out = dst + (size_t)blockIdx.y * 65536;
  int idx = blockIdx.x * 256 + threadIdx.x;
  int k = idx >> 8, c = idx & 255;
  out[c * 256 + k] = f2bf(in[idx]);
}

// -------- weight transpose+convert: W fp32 [K][Nc] -> Wt bf16 [Nc][K] --------
__global__ void k_transpose(const float* __restrict__ in, u16* __restrict__ out, int K, int Nc, int n) {
  int idx = blockIdx.x * 256 + threadIdx.x;
  if (idx < n) {
    int k = idx / Nc, c = idx - k * Nc;
    out[c * K + k] = f2bf(in[idx]);
  }
}

// -------- fp32 -> bf16 convert (adj) --------
__global__ void k_cvt(const float* __restrict__ in, u16* __restrict__ out, int n) {
  int idx = blockIdx.x * 256 + threadIdx.x;
  if (idx < n) out[idx] = f2bf(in[idx]);
}

// ------- LN of fp32 input x -> A = LN(x)*g+b (bf16); no X copy -------
__global__ __launch_bounds__(256) void k_ln_in(const float* __restrict__ x,
                                               u16* __restrict__ A, const float* __restrict__ g,
                                               const float* __restrict__ b) {
  int wv = threadIdx.x >> 6, lane = threadIdx.x & 63;
  long tok = (long)blockIdx.x * 4 + wv;
  int c = lane * 4;
  long off = tok * CC + c;
  float4 v = *(const float4*)(x + off);
  float s = v.x + v.y + v.z + v.w;
  float sq = v.x * v.x + v.y * v.y + v.z * v.z + v.w * v.w;
  s = wsum(s); sq = wsum(sq);
  float m = s * (1.0f / CC);
  float rs = rsqrtf(sq * (1.0f / CC) - m * m + 1e-5f);
  float4 gv = *(const float4*)(g + c);
  float4 bv = *(const float4*)(b + c);
  ushort4 o;
  o.x = f2bf((v.x - m) * rs * gv.x + bv.x);
  o.y = f2bf((v.y - m) * rs * gv.y + bv.y);
  o.z = f2bf((v.z - m) * rs * gv.z + bv.z);
  o.w = f2bf((v.w - m) * rs * gv.w + bv.w);
  *(ushort4*)(A + off) = o;
}

// ---------------- A = LN(X fp32)*g+b ----------------
__global__ __launch_bounds__(256) void k_ln_f32(const float* __restrict__ X, u16* __restrict__ A,
                                                const float* __restrict__ g, const float* __restrict__ b) {
  int wv = threadIdx.x >> 6, lane = threadIdx.x & 63;
  long tok = (long)blockIdx.x * 4 + wv;
  int c = lane * 4;
  long off = tok * CC + c;
  float4 v = *(const float4*)(X + off);
  float s = v.x + v.y + v.z + v.w;
  float sq = v.x * v.x + v.y * v.y + v.z * v.z + v.w * v.w;
  s = wsum(s); sq = wsum(sq);
  float m = s * (1.0f / CC);
  float rs = rsqrtf(sq * (1.0f / CC) - m * m + 1e-5f);
  float4 gv = *(const float4*)(g + c);
  float4 bv = *(const float4*)(b + c);
  ushort4 o;
  o.x = f2bf((v.x - m) * rs * gv.x + bv.x);
  o.y = f2bf((v.y - m) * rs * gv.y + bv.y);
  o.z = f2bf((v.z - m) * rs * gv.z + bv.z);
  o.w = f2bf((v.w - m) * rs * gv.w + bv.w);
  *(ushort4*)(A + off) = o;
}

// ------- spatial combine: reads pristine x; xs = LN1(x); o = LN(P)*s_ng+s_nb;
//         X = x + xs + s_gamma*o (first write of X); A = LN2(X) -------
__global__ __launch_bounds__(256) void k_sp_combine(const float* __restrict__ xin, float* __restrict__ X,
                                                    u16* __restrict__ A, const u16* __restrict__ P,
                                                    const float* __restrict__ n1g, const float* __restrict__ n1b,
                                                    const float* __restrict__ sg,
                                                    const float* __restrict__ s_ng, const float* __restrict__ s_nb,
                                                    const float* __restrict__ n2g, const float* __restrict__ n2b) {
  int wv = threadIdx.x >> 6, lane = threadIdx.x & 63;
  long tok = (long)blockIdx.x * 4 + wv;
  int c = lane * 4;
  long off = tok * CC + c;
  float4 xv = *(const float4*)(xin + off);
  float s1 = xv.x + xv.y + xv.z + xv.w;
  float q1 = xv.x * xv.x + xv.y * xv.y + xv.z * xv.z + xv.w * xv.w;
  s1 = wsum(s1); q1 = wsum(q1);
  float m1 = s1 * (1.0f / CC);
  float r1 = rsqrtf(q1 * (1.0f / CC) - m1 * m1 + 1e-5f);
  float4 g1 = *(const float4*)(n1g + c);
  float4 b1 = *(const float4*)(n1b + c);
  float xs0 = (xv.x - m1) * r1 * g1.x + b1.x;
  float xs1 = (xv.y - m1) * r1 * g1.y + b1.y;
  float xs2 = (xv.z - m1) * r1 * g1.z + b1.z;
  float xs3 = (xv.w - m1) * r1 * g1.w + b1.w;
  ushort4 up = *(const ushort4*)(P + off);
  float4 p = make_float4(bf2f(up.x), bf2f(up.y), bf2f(up.z), bf2f(up.w));
  float s = p.x + p.y + p.z + p.w;
  float sq = p.x * p.x + p.y * p.y + p.z * p.z + p.w * p.w;
  s = wsum(s); sq = wsum(sq);
  float m = s * (1.0f / CC);
  float rs = rsqrtf(sq * (1.0f / CC) - m * m + 1e-5f);
  float4 ug = *(const float4*)(s_ng + c);
  float4 ub = *(const float4*)(s_nb + c);
  float o0 = (p.x - m) * rs * ug.x + ub.x;
  float o1 = (p.y - m) * rs * ug.y + ub.y;
  float o2 = (p.z - m) * rs * ug.z + ub.z;
  float o3 = (p.w - m) * rs * ug.w + ub.w;
  float gsg = sg[0];
  float x0 = xv.x + xs0 + gsg * o0;
  float x1 = xv.y + xs1 + gsg * o1;
  float x2 = xv.z + xs2 + gsg * o2;
  float x3 = xv.w + xs3 + gsg * o3;
  *(float4*)(X + off) = make_float4(x0, x1, x2, x3);
  float s2 = x0 + x1 + x2 + x3;
  float sq2 = x0 * x0 + x1 * x1 + x2 * x2 + x3 * x3;
  s2 = wsum(s2); sq2 = wsum(sq2);
  float m2 = s2 * (1.0f / CC);
  float rs2 = rsqrtf(sq2 * (1.0f / CC) - m2 * m2 + 1e-5f);
  float4 g2 = *(const float4*)(n2g + c);
  float4 b2 = *(const float4*)(n2b + c);
  ushort4 o;
  o.x = f2bf((x0 - m2) * rs2 * g2.x + b2.x);
  o.y = f2bf((x1 - m2) * rs2 * g2.y + b2.y);
  o.z = f2bf((x2 - m2) * rs2 * g2.z + b2.z);
  o.w = f2bf((x3 - m2) * rs2 * g2.w + b2.w);
  *(ushort4*)(A + off) = o;
}

// ---- 256x128-tile 8-wave MFMA GEMM: out[M,Nc] = act[M,Kd](lda) @ Wt[Nc,Kd](ldb)^T ----
// Round-3 schedule kept verbatim (BK=32, 3-buffer, depth-2 counted vmcnt, XOR swizzle, setprio).
// Tile widened to BM=256/8 waves (wave grid 4x2, per-wave 64x64 = same acc[4][4], same 16
// MFMA/barrier-round): LDS 72KB -> 2 blocks x 8 waves = 16 waves/CU (vs 8) and staging
// bytes/output -25%. TLP is what this regime rewards (r4/r7 occupancy-cliff lessons).
// epi: 0 plain; 1 +bias; 2 +bias,gelu; 3 (+bias), Xacc += gamma*val.
__global__ __launch_bounds__(512, 4) void k_gemm(const u16* __restrict__ act, const u16* __restrict__ Wt,
                                                 const float* __restrict__ bias, const float* __restrict__ gptr,
                                                 u16* __restrict__ outB, float* __restrict__ Xacc,
                                                 int Kd, int Nc, int lda, int ldb, int epi, int remap) {
  __shared__ __align__(16) u16 smem[3 * 12288];  // 73728 B: 3 x (As 256x32 | Bs 128x32); epilogue aliases
  int gx = gridDim.x;
  int nwg = gx * gridDim.y;
  int lid = blockIdx.y * gx + blockIdx.x;
  if ((nwg & 7) == 0) lid = (lid & 7) * (nwg >> 3) + (lid >> 3);  // XCD-chunked (all grids %8==0)
  int m0 = (lid / gx) * 256, n0 = (lid % gx) * 128;
  int tid = threadIdx.x;
  int wv = tid >> 6, lane = tid & 63, lm = lane & 15, quad = lane >> 4;
  int wr = wv >> 1, wc = wv & 1;                 // wave grid 4(M) x 2(N); per-wave 64x64 out
  f32x4 acc[4][4];
#pragma unroll
  for (int i = 0; i < 4; i++)
#pragma unroll
    for (int j = 0; j < 4; j++) acc[i][j] = (f32x4){0.f, 0.f, 0.f, 0.f};

  // staging: A chunks cid = j*512 + tid (j<2, rows j*128 + tid>>2); B chunk cid = tid (rows tid>>2).
  // seg = tid&3; source seg pre-swizzled by (row>>1)&3 = (tid>>3)&3 (j*128, j*0 contribute 0 mod 4).
  int srow = tid >> 2;
  int sseg = (tid & 3) ^ ((srow >> 1) & 3);
  const u16* pa = act + (long)(m0 + srow) * lda + sseg * 8;
  const u16* pb = Wt + (long)(n0 + srow) * ldb + sseg * 8;

  auto STAGE = [&](int buf, int kk) {
    u16* sb = smem + buf * 12288;  // As 8192 u16 | Bs 4096 u16
#pragma unroll
    for (int j = 0; j < 2; j++)
      __builtin_amdgcn_global_load_lds(pa + (long)(j * 128) * lda + kk, sb + (j * 512 + wv * 64) * 8, 16, 0, 0);
    __builtin_amdgcn_global_load_lds(pb + kk, sb + 8192 + (wv * 64) * 8, 16, 0, 0);
  };

  int nsteps = Kd >> 5;              // 8 (K=256) or 32 (K=1024)
  STAGE(0, 0);
  STAGE(1, 32);
  asm volatile("s_waitcnt vmcnt(3)" ::: "memory");   // tile0 landed (3 loads/thread/STAGE); tile1 in flight
  __builtin_amdgcn_sched_barrier(0);
  __builtin_amdgcn_s_barrier();

  int xsw = (lm >> 1) & 3;           // read-side swizzle (row>>1)&3 = (lm>>1)&3 for all fragment rows
  int cur = 0;
  for (int t = 0; t < nsteps; ++t) {
    if (t + 2 < nsteps) {
      int nb = cur + 2; if (nb >= 3) nb -= 3;
      STAGE(nb, (t + 2) << 5);       // depth-2 prefetch
    }
    const u16* As = smem + cur * 12288;
    const u16* Bs = As + 8192;
    bf16x8 af[4], bfv[4];
#pragma unroll
    for (int q = 0; q < 4; q++) {
      af[q] = *(const bf16x8*)&As[(wr * 64 + q * 16 + lm) * 32 + (quad ^ xsw) * 8];
      bfv[q] = *(const bf16x8*)&Bs[(wc * 64 + q * 16 + lm) * 32 + (quad ^ xsw) * 8];
    }
    __builtin_amdgcn_s_setprio(1);
#pragma unroll
    for (int ti = 0; ti < 4; ti++)
#pragma unroll
      for (int tj = 0; tj < 4; tj++)
        acc[ti][tj] = __builtin_amdgcn_mfma_f32_16x16x32_bf16(af[ti], bfv[tj], acc[ti][tj], 0, 0, 0);
    __builtin_amdgcn_s_setprio(0);
    asm volatile("s_waitcnt lgkmcnt(0)" ::: "memory");          // my ds_reads done -> buf reusable
    __builtin_amdgcn_sched_barrier(0);
    if (t + 2 < nsteps) asm volatile("s_waitcnt vmcnt(3)" ::: "memory");  // tile t+1 landed (t+2 stays in flight)
    else                asm volatile("s_waitcnt vmcnt(0)" ::: "memory");  // drain tail
    __builtin_amdgcn_sched_barrier(0);
    __builtin_amdgcn_s_barrier();
    cur += 1; if (cur >= 3) cur -= 3;
  }

  // ---- epilogue: rows = m0 + wr*64 + ti*16 + quad*4 + r; cols = n0 + wc*64 + tj*16 + lm ----
  if (epi == 3) {
    float gm = gptr ? gptr[0] : 1.0f;
    float* fs = (float*)smem;  // 64 x 132 fp32 = 33792 B per quarter
#pragma unroll
    for (int qp = 0; qp < 4; qp++) {
      if (qp) __syncthreads();
      if (wr == qp) {
#pragma unroll
        for (int tj = 0; tj < 4; tj++) {
          int col = wc * 64 + tj * 16 + lm;
          float bv = bias ? bias[n0 + col] : 0.0f;
#pragma unroll
          for (int ti = 0; ti < 4; ti++)
#pragma unroll
            for (int r = 0; r < 4; r++)
              fs[(ti * 16 + quad * 4 + r) * 132 + col] = gm * (acc[ti][tj][r] + bv);
        }
      }
      __syncthreads();
      // coalesced float4 RMW of 64 rows x 128 cols (2048 chunks / 512 thr = 4 iters)
#pragma unroll
      for (int p = 0; p < 4; p++) {
        int idx = p * 512 + tid;
        int row = idx >> 5, c4 = idx & 31;
        int grow = remap_row(m0 + qp * 64 + row, remap);
        float* gp = Xacc + (long)grow * Nc + n0 + c4 * 4;
        float4 xv = *(float4*)gp;
        float4 sv = *(const float4*)&fs[row * 132 + c4 * 4];
        xv.x += sv.x; xv.y += sv.y; xv.z += sv.z; xv.w += sv.w;
        *(float4*)gp = xv;
      }
    }
  } else {
    // stage C in LDS (256 x 136 u16 = 69632 B, stride de-conflicts banks), then uint4 streams
#pragma unroll
    for (int tj = 0; tj < 4; tj++) {
      int col = wc * 64 + tj * 16 + lm;
      float bv = (epi >= 1 && bias) ? bias[n0 + col] : 0.0f;
#pragma unroll
      for (int ti = 0; ti < 4; ti++)
#pragma unroll
        for (int r = 0; r < 4; r++) {
          float vv = acc[ti][tj][r] + bv;
          if (epi == 2) vv = gelu_f(vv);
          smem[(wr * 64 + ti * 16 + quad * 4 + r) * 136 + col] = f2bf(vv);
        }
    }
    __syncthreads();
#pragma unroll
    for (int p = 0; p < 8; p++) {
      int idx = p * 512 + tid;             // 4096 uint4 chunks of the 256x128 tile
      int row = idx >> 4, c8 = idx & 15;
      int grow = remap_row(m0 + row, remap);
      *(uint4*)(outB + (long)grow * Nc + n0 + c8 * 8) = *(const uint4*)&smem[row * 136 + c8 * 8];
    }
  }
}

// ---- spatial attention, HEAD-LOOP: one block per (b,t) frame, 8 heads sequential. ----
__global__ __launch_bounds__(384) void k_sp_attn(const u16* __restrict__ QKV, const u16* __restrict__ adj,
                                                 u16* __restrict__ O) {
  __shared__ __align__(16) u16 Qs[96 * 32];
  __shared__ __align__(16) u16 Ks[96 * 32];
  __shared__ __align__(16) u16 Vt[32 * 104];   // V^T: [dim][token], stride 104
  __shared__ __align__(16) u16 Ss[96 * 104];   // adj then P, stride 104
  int blk = blockIdx.x;
  blk = (blk & 7) * ((int)gridDim.x >> 3) + (blk >> 3);  // XCD-chunked (768 % 8 == 0)
  int t = blk % TT, b = blk / TT;
  long fQ = ((long)(b * TT + t) * EE) * 768;
  long fO = ((long)(b * TT + t) * EE) * CC;
  int tid = threadIdx.x;
  int row = tid >> 2, seg = tid & 3;
  int wv = tid >> 6, lane = tid & 63, lm = lane & 15, quad = lane >> 4;
  long gq0 = fQ + (long)row * 768 + seg * 8;
  uint4 rq = *(const uint4*)(QKV + gq0);
  uint4 rk = *(const uint4*)(QKV + gq0 + 256);
  uint4 rv = *(const uint4*)(QKV + gq0 + 512);
  int cb = seg * 24;
  for (int h = 0; h < 8; ++h) {
    *(uint4*)&Qs[row * 32 + seg * 8] = rq;
    *(uint4*)&Ks[row * 32 + seg * 8] = rk;
    { union { uint4 u; u16 s[8]; } vv; vv.u = rv;
#pragma unroll
      for (int i = 0; i < 8; i++) Vt[(seg * 8 + i) * 104 + row] = vv.s[i]; }
#pragma unroll
    for (int i = 0; i < 3; i++)
      *(uint4*)&Ss[row * 104 + cb + i * 8] = *(const uint4*)(adj + row * 96 + cb + i * 8);
    __syncthreads();
    if (h < 7) {  // T14: prefetch next head's QKV under this head's compute
      long g = gq0 + (h + 1) * 32;
      rq = *(const uint4*)(QKV + g);
      rk = *(const uint4*)(QKV + g + 256);
      rv = *(const uint4*)(QKV + g + 512);
      __builtin_amdgcn_sched_barrier(0);
    }
    bf16x8 aq = *(const bf16x8*)&Qs[(wv * 16 + lm) * 32 + quad * 8];
    f32x4 sc[6];
#pragma unroll
    for (int j = 0; j < 6; j++) {
      bf16x8 bk = *(const bf16x8*)&Ks[(j * 16 + lm) * 32 + quad * 8];
      f32x4 z = (f32x4){0.f, 0.f, 0.f, 0.f};
      sc[j] = __builtin_amdgcn_mfma_f32_16x16x32_bf16(aq, bk, z, 0, 0, 0);
    }
    u16 sv[6][4];
#pragma unroll
    for (int j = 0; j < 6; j++) {
      int col = j * 16 + lm;
#pragma unroll
      for (int r = 0; r < 4; r++) {
        int rrow = wv * 16 + quad * 4 + r;
        float a = bf2f(Ss[rrow * 104 + col]);
        sv[j][r] = f2bf((sc[j][r] * a + 1.0f) * 0.5f);
      }
    }
    __syncthreads();
#pragma unroll
    for (int j = 0; j < 6; j++) {
      int col = j * 16 + lm;
#pragma unroll
      for (int r = 0; r < 4; r++) Ss[(wv * 16 + quad * 4 + r) * 104 + col] = sv[j][r];
    }
    __syncthreads();
    f32x4 oc[2];
    oc[0] = (f32x4){0.f, 0.f, 0.f, 0.f};
    oc[1] = (f32x4){0.f, 0.f, 0.f, 0.f};
#pragma unroll
    for (int ks = 0; ks < 3; ks++) {
      bf16x8 as = *(const bf16x8*)&Ss[(wv * 16 + lm) * 104 + ks * 32 + quad * 8];
#pragma unroll
      for (int n = 0; n < 2; n++) {
        bf16x8 bv = *(const bf16x8*)&Vt[(n * 16 + lm) * 104 + ks * 32 + quad * 8];
        oc[n] = __builtin_amdgcn_mfma_f32_16x16x32_bf16(as, bv, oc[n], 0, 0, 0);
      }
    }
#pragma unroll
    for (int n = 0; n < 2; n++)
#pragma unroll
      for (int r = 0; r < 4; r++) {
        int rrow = wv * 16 + quad * 4 + r;
        O[fO + (long)rrow * CC + h * DDm + n * 16 + lm] = f2bf(oc[n][r]);
      }
    __syncthreads();
  }
}

// ---- temporal attention, HEAD-LOOP: one block per (b,e); register softmax per head. ----
__global__ __launch_bounds__(384) void k_tp_attn(const u16* __restrict__ QKV, u16* __restrict__ O) {
  __shared__ __align__(16) u16 Qs[96 * 32];
  __shared__ __align__(16) u16 Ks[96 * 32];
  __shared__ __align__(16) u16 Vt[32 * 104];   // V^T: [dim][token]
  __shared__ __align__(16) u16 Ss[96 * 104];   // P in bf16, stride 104
  int blk = blockIdx.x;
  blk = (blk & 7) * ((int)gridDim.x >> 3) + (blk >> 3);  // XCD-chunked
  int e = blk % EE, b = blk / EE;
  long fQ = ((long)(b * EE + e) * TT) * 768;
  long fO = ((long)(b * EE + e) * TT) * CC;
  int tid = threadIdx.x;
  int row = tid >> 2, seg = tid & 3;
  int wv = tid >> 6, lane = tid & 63, lm = lane & 15, quad = lane >> 4;
  long gq0 = fQ + (long)row * 768 + seg * 8;
  uint4 rq = *(const uint4*)(QKV + gq0);
  uint4 rk = *(const uint4*)(QKV + gq0 + 256);
  uint4 rv = *(const uint4*)(QKV + gq0 + 512);
  const float scale = 0.17677669529663687f;  // 1/sqrt(32)
  for (int h = 0; h < 8; ++h) {
    *(uint4*)&Qs[row * 32 + seg * 8] = rq;
    *(uint4*)&Ks[row * 32 + seg * 8] = rk;
    { union { uint4 u; u16 s[8]; } vv; vv.u = rv;
#pragma unroll
      for (int i = 0; i < 8; i++) Vt[(seg * 8 + i) * 104 + row] = vv.s[i]; }
    __syncthreads();
    if (h < 7) {
      long g = gq0 + (h + 1) * 32;
      rq = *(const uint4*)(QKV + g);
      rk = *(const uint4*)(QKV + g + 256);
      rv = *(const uint4*)(QKV + g + 512);
      __builtin_amdgcn_sched_barrier(0);
    }
    bf16x8 aq = *(const bf16x8*)&Qs[(wv * 16 + lm) * 32 + quad * 8];
    f32x4 sc[6];
#pragma unroll
    for (int j = 0; j < 6; j++) {
      bf16x8 bk = *(const bf16x8*)&Ks[(j * 16 + lm) * 32 + quad * 8];
      f32x4 z = (f32x4){0.f, 0.f, 0.f, 0.f};
      sc[j] = __builtin_amdgcn_mfma_f32_16x16x32_bf16(aq, bk, z, 0, 0, 0);
    }
#pragma unroll
    for (int r = 0; r < 4; r++) {
      float mx = -1e30f;
#pragma unroll
      for (int j = 0; j < 6; j++) { sc[j][r] *= scale; mx = fmaxf(mx, sc[j][r]); }
#pragma unroll
      for (int mask = 1; mask < 16; mask <<= 1) mx = fmaxf(mx, __shfl_xor(mx, mask));
      float sum = 0.f;
#pragma unroll
      for (int j = 0; j < 6; j++) { float p = __expf(sc[j][r] - mx); sc[j][r] = p; sum += p; }
#pragma unroll
      for (int mask = 1; mask < 16; mask <<= 1) sum += __shfl_xor(sum, mask);
      float inv = 1.0f / sum;
#pragma unroll
      for (int j = 0; j < 6; j++) sc[j][r] *= inv;
    }
#pragma unroll
    for (int j = 0; j < 6; j++) {
      int col = j * 16 + lm;
#pragma unroll
      for (int r = 0; r < 4; r++) Ss[(wv * 16 + quad * 4 + r) * 104 + col] = f2bf(sc[j][r]);
    }
    __syncthreads();
    f32x4 oc[2];
    oc[0] = (f32x4){0.f, 0.f, 0.f, 0.f};
    oc[1] = (f32x4){0.f, 0.f, 0.f, 0.f};
#pragma unroll
    for (int ks = 0; ks < 3; ks++) {
      bf16x8 as = *(const bf16x8*)&Ss[(wv * 16 + lm) * 104 + ks * 32 + quad * 8];
#pragma unroll
      for (int n = 0; n < 2; n++) {
        bf16x8 bv = *(const bf16x8*)&Vt[(n * 16 + lm) * 104 + ks * 32 + quad * 8];
        oc[n] = __builtin_amdgcn_mfma_f32_16x16x32_bf16(as, bv, oc[n], 0, 0, 0);
      }
    }
#pragma unroll
    for (int n = 0; n < 2; n++)
#pragma unroll
      for (int r = 0; r < 4; r++) {
        int rrow = wv * 16 + quad * 4 + r;  // t index
        O[fO + (long)rrow * CC + h * DDm + n * 16 + lm] = f2bf(oc[n][r]);
      }
    __syncthreads();
  }
}

// ------- downsample: out[b,i,e,c] = 0.5*(X[b,2i,e,c] + X[b,2i+1,e,c])  (fp32 out) -------
__global__ __launch_bounds__(256) void k_down(const float* __restrict__ X, float* __restrict__ out) {
  long i4 = ((long)blockIdx.x * 256 + threadIdx.x) * 4;
  long tmp = i4;
  int c = (int)(tmp & 255); tmp >>= 8;
  int e = (int)(tmp % EE); tmp /= EE;
  int i = (int)(tmp % TOUT);
  int b = (int)(tmp / TOUT);
  long src0 = (((long)b * TT + 2 * i) * EE + e) * CC + c;
  float4 a = *(const float4*)(X + src0);
  float4 bb = *(const float4*)(X + src0 + (long)EE * CC);
  float4 o = make_float4(0.5f * (a.x + bb.x), 0.5f * (a.y + bb.y),
                         0.5f * (a.z + bb.z), 0.5f * (a.w + bb.w));
  *(float4*)(out + i4) = o;
}

extern "C" void kernel_launch(void* const* d_in, const int* in_sizes, int n_in,
                              void* d_out, int out_size, void* d_ws, size_t ws_size,
                              hipStream_t stream) {
  (void)in_sizes; (void)n_in; (void)out_size; (void)ws_size;
  const float* x   = (const float*)d_in[0];
  const float* adj = (const float*)d_in[1];
  const float* n1g = (const float*)d_in[2];
  const float* n1b = (const float*)d_in[3];
  const float* swq = (const float*)d_in[4];
  const float* swk = (const float*)d_in[5];
  const float* swv = (const float*)d_in[6];
  const float* swp = (const float*)d_in[7];
  const float* sbp = (const float*)d_in[8];
  const float* sng = (const float*)d_in[9];
  const float* snb = (const float*)d_in[10];
  const float* sg  = (const float*)d_in[11];
  const float* n2g = (const float*)d_in[12];
  const float* n2b = (const float*)d_in[13];
  const float* twq = (const float*)d_in[14];
  const float* twk = (const float*)d_in[15];
  const float* twv = (const float*)d_in[16];
  const float* twp = (const float*)d_in[17];
  const float* tbp = (const float*)d_in[18];
  const float* tg  = (const float*)d_in[19];
  const float* n3g = (const float*)d_in[20];
  const float* n3b = (const float*)d_in[21];
  const float* mw1 = (const float*)d_in[22];
  const float* mb1 = (const float*)d_in[23];
  const float* mw2 = (const float*)d_in[24];
  const float* mb2 = (const float*)d_in[25];
  float* out = (float*)d_out;

  // ---- workspace: X fp32 | A bf16 | QKV bf16 [N,768] | weights ----
  size_t nc = (size_t)NTOK * CC;
  float* X  = (float*)d_ws;
  u16* A    = (u16*)(X + nc);
  u16* QKV  = A + nc;
  u16* Pb   = QKV;
  u16* Hh   = QKV;    // MLP: [N/2, 1024] = 75.5 MB fits in QKV (113 MB)
  u16* wts  = QKV + 3 * nc;
  u16* swq_t = wts;
  u16* swp_t = wts + 3 * 65536;
  u16* twq_t = wts + 4 * 65536;
  u16* twp_t = wts + 7 * 65536;
  u16* w1_t  = wts + 8 * 65536;  // [1024,256]
  u16* w2_t  = w1_t + 262144;    // [256,1024]
  u16* adj_b = w2_t + 262144;    // [96,96]

  WPtr8 w8; w8.p[0] = swq; w8.p[1] = swk; w8.p[2] = swv; w8.p[3] = swp;
  w8.p[4] = twq; w8.p[5] = twk; w8.p[6] = twv; w8.p[7] = twp;
  k_transpose8<<<dim3(256, 8), 256, 0, stream>>>(w8, wts);
  k_transpose<<<(256 * 1024 + 255) / 256, 256, 0, stream>>>(mw1, w1_t, 256, 1024, 256 * 1024);
  k_transpose<<<(1024 * 256 + 255) / 256, 256, 0, stream>>>(mw2, w2_t, 1024, 256, 1024 * 256);
  k_cvt<<<(EE * EE + 255) / 256, 256, 0, stream>>>(adj, adj_b, EE * EE);

  auto gemm = [&](const u16* act, const u16* Wt, const float* bias, const float* gamma,
                  u16* outB, float* Xacc, int Kd, int Nc, int lda, int ldb, int epi, int remap, int M) {
    dim3 g(Nc / 128, M / 256);
    k_gemm<<<g, 512, 0, stream>>>(act, Wt, bias, gamma, outB, Xacc, Kd, Nc, lda, ldb, epi, remap);
  };

  int lnBlocks = NTOK / 4;

  // ---- spatial block ----
  k_ln_in<<<lnBlocks, 256, 0, stream>>>(x, A, n1g, n1b);                          // A = xs
  gemm(A, swq_t, nullptr, nullptr, QKV, nullptr, 256, 768, 256, 256, 0, 0, NTOK); // fused QKV (6x288)
  k_sp_attn<<<BB * TT, 384, 0, stream>>>(QKV, adj_b, A);                          // O -> A (head loop)
  gemm(A, swp_t, sbp, nullptr, Pb, nullptr, 256, 256, 256, 256, 1, 0, NTOK);      // P -> Pb (2x288)
  k_sp_combine<<<lnBlocks, 256, 0, stream>>>(x, X, A, Pb, n1g, n1b, sg, sng, snb, n2g, n2b);

  // ---- temporal block (token order [b,e,t] inside) ----
  gemm(A, twq_t, nullptr, nullptr, QKV, nullptr, 256, 768, 256, 256, 0, 1, NTOK); // fused QKV, bte->bet
  k_tp_attn<<<BB * EE, 384, 0, stream>>>(QKV, A);                                 // O -> A (bet, head loop)
  gemm(A, twp_t, tbp, tg, nullptr, X, 256, 256, 256, 256, 3, 2, NTOK);            // X += g*(O@wp+b), bet->bte

  // ---- MLP: token-split halves, full HID=1024 each (X RMW once per token) ----
  k_ln_f32<<<lnBlocks, 256, 0, stream>>>(X, A, n3g, n3b);                         // A = xm
  for (int hf = 0; hf < 2; hf++) {
    long r0 = (long)hf * (NTOK / 2);
    gemm(A + r0 * CC, w1_t, mb1, nullptr, Hh, nullptr, 256, 1024, 256, 256, 2, 0, NTOK / 2);   // 8x144
    gemm(Hh, w2_t, mb2, nullptr, nullptr, X + r0 * CC, 1024, 256, 1024, 1024, 3, 0, NTOK / 2); // 2x144
  }

  // ---- downsample (fp32 out) ----
  long outElems = (long)BB * TOUT * EE * CC;
  k_down<<<(int)(outElems / 4 / 256), 256, 0, stream>>>(X, out);
}

// Round 10
// 682.544 us; speedup vs baseline: 1.6220x; 1.0085x over previous
//
#include <hip/hip_runtime.h>
#include <cmath>

constexpr int BB = 8, TT = 96, EE = 96, CC = 256, HHD = 8, DDm = 32;
constexpr int NTOK = BB * TT * EE;   // 73728
constexpr int TOUT = TT / 2;         // 48

typedef unsigned short u16;
typedef short bf16x8 __attribute__((ext_vector_type(8)));
typedef float f32x4 __attribute__((ext_vector_type(4)));

__device__ __forceinline__ float bf2f(u16 u) {
  union { unsigned int i; float f; } v; v.i = ((unsigned int)u) << 16; return v.f;
}
__device__ __forceinline__ u16 f2bf(float f) {
  union { unsigned int i; float f; } v; v.f = f;
  return (u16)((v.i + 0x7FFFu + ((v.i >> 16) & 1u)) >> 16);  // RNE
}
__device__ __forceinline__ float wsum(float v) {
#pragma unroll
  for (int off = 32; off; off >>= 1) v += __shfl_xor(v, off);
  return v;
}
__device__ __forceinline__ float gelu_f(float x) {
  return 0.5f * x * (1.0f + erff(x * 0.70710678118654752f));
}
// token-order permutations: 0=id, 1=[b,t,e]->[b,e,t] position, 2=[b,e,t]->[b,t,e]
__device__ __forceinline__ int remap_row(int row, int mode) {
  if (mode == 0) return row;
  int b = row / (TT * EE);
  int rem = row - b * (TT * EE);
  if (mode == 1) { int t = rem / EE, e = rem - t * EE; return (b * EE + e) * TT + t; }
  int e = rem / TT, t = rem - e * TT;
  return (b * TT + t) * EE + e;
}

// -------- batched weight transpose+convert: 8 x [256,256] fp32 -> bf16 [Nc][K] --------
struct WPtr8 { const float* p[8]; };
__global__ void k_transpose8(WPtr8 src, u16* __restrict__ dst) {
  const float* in = src.p[blockIdx.y];
  u16* out = dst + (size_t)blockIdx.y * 65536;
  int idx = blockIdx.x * 256 + threadIdx.x;
  int k = idx >> 8, c = idx & 255;
  out[c * 256 + k] = f2bf(in[idx]);
}

// -------- weight transpose+convert: W fp32 [K][Nc] -> Wt bf16 [Nc][K] --------
__global__ void k_transpose(const float* __restrict__ in, u16* __restrict__ out, int K, int Nc, int n) {
  int idx = blockIdx.x * 256 + threadIdx.x;
  if (idx < n) {
    int k = idx / Nc, c = idx - k * Nc;
    out[c * K + k] = f2bf(in[idx]);
  }
}

// -------- fp32 -> bf16 convert (adj) --------
__global__ void k_cvt(const float* __restrict__ in, u16* __restrict__ out, int n) {
  int idx = blockIdx.x * 256 + threadIdx.x;
  if (idx < n) out[idx] = f2bf(in[idx]);
}

// ------- LN of fp32 input x -> A = LN(x)*g+b (bf16); no X copy -------
__global__ __launch_bounds__(256) void k_ln_in(const float* __restrict__ x,
                                               u16* __restrict__ A, const float* __restrict__ g,
                                               const float* __restrict__ b) {
  int wv = threadIdx.x >> 6, lane = threadIdx.x & 63;
  long tok = (long)blockIdx.x * 4 + wv;
  int c = lane * 4;
  long off = tok * CC + c;
  float4 v = *(const float4*)(x + off);
  float s = v.x + v.y + v.z + v.w;
  float sq = v.x * v.x + v.y * v.y + v.z * v.z + v.w * v.w;
  s = wsum(s); sq = wsum(sq);
  float m = s * (1.0f / CC);
  float rs = rsqrtf(sq * (1.0f / CC) - m * m + 1e-5f);
  float4 gv = *(const float4*)(g + c);
  float4 bv = *(const float4*)(b + c);
  ushort4 o;
  o.x = f2bf((v.x - m) * rs * gv.x + bv.x);
  o.y = f2bf((v.y - m) * rs * gv.y + bv.y);
  o.z = f2bf((v.z - m) * rs * gv.z + bv.z);
  o.w = f2bf((v.w - m) * rs * gv.w + bv.w);
  *(ushort4*)(A + off) = o;
}

// ---------------- A = LN(X fp32)*g+b ----------------
__global__ __launch_bounds__(256) void k_ln_f32(const float* __restrict__ X, u16* __restrict__ A,
                                                const float* __restrict__ g, const float* __restrict__ b) {
  int wv = threadIdx.x >> 6, lane = threadIdx.x & 63;
  long tok = (long)blockIdx.x * 4 + wv;
  int c = lane * 4;
  long off = tok * CC + c;
  float4 v = *(const float4*)(X + off);
  float s = v.x + v.y + v.z + v.w;
  float sq = v.x * v.x + v.y * v.y + v.z * v.z + v.w * v.w;
  s = wsum(s); sq = wsum(sq);
  float m = s * (1.0f / CC);
  float rs = rsqrtf(sq * (1.0f / CC) - m * m + 1e-5f);
  float4 gv = *(const float4*)(g + c);
  float4 bv = *(const float4*)(b + c);
  ushort4 o;
  o.x = f2bf((v.x - m) * rs * gv.x + bv.x);
  o.y = f2bf((v.y - m) * rs * gv.y + bv.y);
  o.z = f2bf((v.z - m) * rs * gv.z + bv.z);
  o.w = f2bf((v.w - m) * rs * gv.w + bv.w);
  *(ushort4*)(A + off) = o;
}

// ---- 128x128-tile MFMA GEMM: out[M,Nc] = act[M,Kd](lda) @ Wt[Nc,Kd](ldb)^T ----
// ROUND-3 VERIFIED CONFIG: BK=32, 3-buffer LDS (49KB, 3 blk/CU), depth-2 prefetch vmcnt(4),
// seg XOR-swizzle (rule-21 both-sides), setprio, sched_barrier guards.
__global__ __launch_bounds__(256) void k_gemm128(const u16* __restrict__ act, const u16* __restrict__ Wt,
                                                 const float* __restrict__ bias, const float* __restrict__ gptr,
                                                 u16* __restrict__ outB, float* __restrict__ Xacc,
                                                 int Kd, int Nc, int lda, int ldb, int epi, int remap) {
  __shared__ __align__(16) u16 smem[3 * 8192];   // 49152 B: 3 x (As 4096 + Bs 4096); epilogue aliases
  int gx = gridDim.x;
  int nwg = gx * gridDim.y;
  int lid = blockIdx.y * gx + blockIdx.x;
  if ((nwg & 7) == 0) lid = (lid & 7) * (nwg >> 3) + (lid >> 3);  // XCD-chunked (bijective: nwg%8==0)
  int m0 = (lid / gx) * 128, n0 = (lid % gx) * 128;
  int tid = threadIdx.x;
  int wv = tid >> 6, lane = tid & 63, lm = lane & 15, quad = lane >> 4;
  int wr = wv >> 1, wc = wv & 1;
  f32x4 acc[4][4];
#pragma unroll
  for (int i = 0; i < 4; i++)
#pragma unroll
    for (int j = 0; j < 4; j++) acc[i][j] = (f32x4){0.f, 0.f, 0.f, 0.f};

  int srow = tid >> 2;
  int sseg = (tid & 3) ^ ((srow >> 1) & 3);
  const u16* pa = act + (long)(m0 + srow) * lda + sseg * 8;
  const u16* pb = Wt + (long)(n0 + srow) * ldb + sseg * 8;

  auto STAGE = [&](int buf, int kk) {
    u16* sb = smem + buf * 8192;  // [As | Bs] per buffer, 4096 u16 each
#pragma unroll
    for (int j = 0; j < 2; j++) {
      __builtin_amdgcn_global_load_lds(pa + (long)j * 64 * lda + kk, sb + (j * 256 + wv * 64) * 8, 16, 0, 0);
      __builtin_amdgcn_global_load_lds(pb + (long)j * 64 * ldb + kk, sb + 4096 + (j * 256 + wv * 64) * 8, 16, 0, 0);
    }
  };

  int nsteps = Kd >> 5;              // always >= 8 here
  STAGE(0, 0);
  STAGE(1, 32);
  asm volatile("s_waitcnt vmcnt(4)" ::: "memory");   // tile0 landed; tile1 in flight
  __builtin_amdgcn_sched_barrier(0);
  __builtin_amdgcn_s_barrier();

  int xsw = (lm >> 1) & 3;           // read-side swizzle: slot = quad ^ xsw (involution of source swizzle)
  int cur = 0;
  for (int t = 0; t < nsteps; ++t) {
    if (t + 2 < nsteps) {
      int nb = cur + 2; if (nb >= 3) nb -= 3;
      STAGE(nb, (t + 2) << 5);       // depth-2 prefetch
    }
    const u16* As = smem + cur * 8192;
    const u16* Bs = As + 4096;
    bf16x8 af[4], bfv[4];
#pragma unroll
    for (int q = 0; q < 4; q++) {
      af[q] = *(const bf16x8*)&As[(wr * 64 + q * 16 + lm) * 32 + (quad ^ xsw) * 8];
      bfv[q] = *(const bf16x8*)&Bs[(wc * 64 + q * 16 + lm) * 32 + (quad ^ xsw) * 8];
    }
    __builtin_amdgcn_s_setprio(1);
#pragma unroll
    for (int ti = 0; ti < 4; ti++)
#pragma unroll
      for (int tj = 0; tj < 4; tj++)
        acc[ti][tj] = __builtin_amdgcn_mfma_f32_16x16x32_bf16(af[ti], bfv[tj], acc[ti][tj], 0, 0, 0);
    __builtin_amdgcn_s_setprio(0);
    asm volatile("s_waitcnt lgkmcnt(0)" ::: "memory");          // my ds_reads done -> buf reusable
    __builtin_amdgcn_sched_barrier(0);
    if (t + 2 < nsteps) asm volatile("s_waitcnt vmcnt(4)" ::: "memory");  // tile t+1 landed (t+2 stays in flight)
    else                asm volatile("s_waitcnt vmcnt(0)" ::: "memory");  // drain tail
    __builtin_amdgcn_sched_barrier(0);
    __builtin_amdgcn_s_barrier();
    cur += 1; if (cur >= 3) cur -= 3;
  }

  if (epi == 3) {
    float gm = gptr ? gptr[0] : 1.0f;
    float* fs = (float*)smem;  // 64 x 132 fp32 = 33792 B
#pragma unroll
    for (int half = 0; half < 2; half++) {
      if (half) __syncthreads();
      if (wr == half) {
#pragma unroll
        for (int tj = 0; tj < 4; tj++) {
          int col = wc * 64 + tj * 16 + lm;
          float bv = bias ? bias[n0 + col] : 0.0f;
#pragma unroll
          for (int ti = 0; ti < 4; ti++)
#pragma unroll
            for (int r = 0; r < 4; r++)
              fs[(ti * 16 + quad * 4 + r) * 132 + col] = gm * (acc[ti][tj][r] + bv);
        }
      }
      __syncthreads();
      // coalesced float4 RMW of 64 rows x 128 cols
#pragma unroll
      for (int p = 0; p < 8; p++) {
        int idx = p * 256 + tid;            // 2048 float4 chunks
        int row = idx >> 5, c4 = idx & 31;
        int grow = remap_row(m0 + half * 64 + row, remap);
        float* gp = Xacc + (long)grow * Nc + n0 + c4 * 4;
        float4 xv = *(float4*)gp;
        float4 sv = *(const float4*)&fs[row * 132 + c4 * 4];
        xv.x += sv.x; xv.y += sv.y; xv.z += sv.z; xv.w += sv.w;
        *(float4*)gp = xv;
      }
    }
  } else {
    // stage C in LDS (row stride 136 u16 de-conflicts banks), then coalesced uint4 writes
#pragma unroll
    for (int tj = 0; tj < 4; tj++) {
      int col = wc * 64 + tj * 16 + lm;
      float bv = (epi >= 1 && bias) ? bias[n0 + col] : 0.0f;
#pragma unroll
      for (int ti = 0; ti < 4; ti++)
#pragma unroll
        for (int r = 0; r < 4; r++) {
          float vv = acc[ti][tj][r] + bv;
          if (epi == 2) vv = gelu_f(vv);
          smem[(wr * 64 + ti * 16 + quad * 4 + r) * 136 + col] = f2bf(vv);
        }
    }
    __syncthreads();
#pragma unroll
    for (int p = 0; p < 8; p++) {
      int idx = p * 256 + tid;             // 2048 uint4 chunks of the 128x128 tile
      int row = idx >> 4, c8 = idx & 15;
      int grow = remap_row(m0 + row, remap);
      *(uint4*)(outB + (long)grow * Nc + n0 + c8 * 8) = *(const uint4*)&smem[row * 136 + c8 * 8];
    }
  }
}

// ---- FUSED spatial projection + combine: P = O@swp + sbp (GEMM, BN=256 full width);
//      epilogue per row: xs = LN1(x); o = LN(P)*s_ng + s_nb; X = x + xs + s_gamma*o;
//      A = LN2(X). Deletes Pb round-trip + separate combine dispatch. P goes acc -> RNE bf16
//      -> LDS: bitwise identical to the old Pb path, numerics unchanged.
// 512 thr = 8 waves (2M x 4N), per-wave 64x64 (verified acc[4][4]); round-3 K-loop verbatim
// (BK=32, tri-buffer 72KB -> 2 blk/CU, depth-2 counted vmcnt(3), XOR swizzle both-sides).
__global__ __launch_bounds__(512, 2) void k_projcmb(const u16* __restrict__ act, const u16* __restrict__ Wt,
                                                    const float* __restrict__ bias,
                                                    const float* __restrict__ xin, float* __restrict__ X,
                                                    u16* __restrict__ Aout,
                                                    const float* __restrict__ n1g, const float* __restrict__ n1b,
                                                    const float* __restrict__ sg,
                                                    const float* __restrict__ s_ng, const float* __restrict__ s_nb,
                                                    const float* __restrict__ n2g, const float* __restrict__ n2b) {
  __shared__ __align__(16) u16 smem[3 * 12288];  // 73728 B: 3 x (As[128][32] 4096 | Bs[256][32] 8192)
  int nwg = gridDim.x;
  int lid = blockIdx.x;
  lid = (lid & 7) * (nwg >> 3) + (lid >> 3);     // XCD-chunked (576 % 8 == 0)
  int m0 = lid * 128;
  int tid = threadIdx.x;
  int wid = tid >> 6, lane = tid & 63, lm = lane & 15, quad = lane >> 4;
  int wm = wid >> 2, wn = wid & 3;               // wave grid 2(M) x 4(N); per-wave 64x64
  f32x4 acc[4][4];
#pragma unroll
  for (int i = 0; i < 4; i++)
#pragma unroll
    for (int j = 0; j < 4; j++) acc[i][j] = (f32x4){0.f, 0.f, 0.f, 0.f};

  // staging coords: row = tid>>2 (A: 0..127; B: +j*128), slot = tid&3; source seg pre-swizzled
  // by (row>>1)&3 = (tid>>3)&3 (j*128 contributes 0 mod 8 -> same for both B halves).
  int srow = tid >> 2;
  int sseg = (tid & 3) ^ ((tid >> 3) & 3);
  const u16* pa = act + (long)(m0 + srow) * CC + sseg * 8;
  const u16* pb = Wt + (long)srow * CC + sseg * 8;

  auto STAGE = [&](int buf, int kk) {            // 3 loads/thread
    u16* sa = smem + buf * 12288;                // As 4096 u16
    u16* sb = sa + 4096;                         // Bs 8192 u16
    __builtin_amdgcn_global_load_lds(pa + kk, sa + (wid * 64) * 8, 16, 0, 0);
#pragma unroll
    for (int j = 0; j < 2; j++)
      __builtin_amdgcn_global_load_lds(pb + (long)(j * 128) * CC + kk, sb + (j * 512 + wid * 64) * 8, 16, 0, 0);
  };

  STAGE(0, 0);
  STAGE(1, 32);
  asm volatile("s_waitcnt vmcnt(3)" ::: "memory");   // tile0 (3 loads) landed; tile1 in flight
  __builtin_amdgcn_sched_barrier(0);
  __builtin_amdgcn_s_barrier();

  int xsw = (lm >> 1) & 3;                       // frag rows ≡ lm mod 16 -> (row>>1)&3 = (lm>>1)&3
  int cur = 0;
#pragma unroll
  for (int t = 0; t < 8; ++t) {                  // Kd = 256 fixed
    if (t + 2 < 8) {
      int nb = cur + 2; if (nb >= 3) nb -= 3;
      STAGE(nb, (t + 2) << 5);                   // depth-2 prefetch
    }
    const u16* As = smem + cur * 12288;
    const u16* Bs = As + 4096;
    bf16x8 af[4], bfv[4];
#pragma unroll
    for (int q = 0; q < 4; q++) {
      af[q] = *(const bf16x8*)&As[(wm * 64 + q * 16 + lm) * 32 + (quad ^ xsw) * 8];
      bfv[q] = *(const bf16x8*)&Bs[(wn * 64 + q * 16 + lm) * 32 + (quad ^ xsw) * 8];
    }
    __builtin_amdgcn_s_setprio(1);
#pragma unroll
    for (int ti = 0; ti < 4; ti++)
#pragma unroll
      for (int tj = 0; tj < 4; tj++)
        acc[ti][tj] = __builtin_amdgcn_mfma_f32_16x16x32_bf16(af[ti], bfv[tj], acc[ti][tj], 0, 0, 0);
    __builtin_amdgcn_s_setprio(0);
    asm volatile("s_waitcnt lgkmcnt(0)" ::: "memory");
    __builtin_amdgcn_sched_barrier(0);
    if (t + 2 < 8) asm volatile("s_waitcnt vmcnt(3)" ::: "memory");
    else           asm volatile("s_waitcnt vmcnt(0)" ::: "memory");
    __builtin_amdgcn_sched_barrier(0);
    __builtin_amdgcn_s_barrier();
    cur += 1; if (cur >= 3) cur -= 3;
  }

  // ---- stage P (bias-added, RNE bf16 — bitwise = old Pb) into Cs[128][264] (67.6 KB) ----
  u16* Cs = smem;
#pragma unroll
  for (int tj = 0; tj < 4; tj++) {
    int col = wn * 64 + tj * 16 + lm;
    float bv = bias[col];
#pragma unroll
    for (int ti = 0; ti < 4; ti++)
#pragma unroll
      for (int r = 0; r < 4; r++)
        Cs[(wm * 64 + ti * 16 + quad * 4 + r) * 264 + col] = f2bf(acc[ti][tj][r] + bv);
  }
  __syncthreads();

  // ---- combine epilogue: wave wid owns rows wid*16 .. +15; 64 lanes x 4 cols = full row ----
  int c = lane * 4;
  float4 g1 = *(const float4*)(n1g + c);
  float4 b1 = *(const float4*)(n1b + c);
  float4 ug = *(const float4*)(s_ng + c);
  float4 ub = *(const float4*)(s_nb + c);
  float4 g2 = *(const float4*)(n2g + c);
  float4 b2 = *(const float4*)(n2b + c);
  float gsg = sg[0];
  for (int rr = 0; rr < 16; ++rr) {
    int row = wid * 16 + rr;
    long off = (long)(m0 + row) * CC + c;
    float4 xv = *(const float4*)(xin + off);
    float s1 = xv.x + xv.y + xv.z + xv.w;
    float q1 = xv.x * xv.x + xv.y * xv.y + xv.z * xv.z + xv.w * xv.w;
    s1 = wsum(s1); q1 = wsum(q1);
    float m1 = s1 * (1.0f / CC);
    float r1 = rsqrtf(q1 * (1.0f / CC) - m1 * m1 + 1e-5f);
    float xs0 = (xv.x - m1) * r1 * g1.x + b1.x;
    float xs1 = (xv.y - m1) * r1 * g1.y + b1.y;
    float xs2 = (xv.z - m1) * r1 * g1.z + b1.z;
    float xs3 = (xv.w - m1) * r1 * g1.w + b1.w;
    ushort4 up = *(const ushort4*)&Cs[row * 264 + c];
    float4 p = make_float4(bf2f(up.x), bf2f(up.y), bf2f(up.z), bf2f(up.w));
    float s = p.x + p.y + p.z + p.w;
    float sq = p.x * p.x + p.y * p.y + p.z * p.z + p.w * p.w;
    s = wsum(s); sq = wsum(sq);
    float m = s * (1.0f / CC);
    float rs = rsqrtf(sq * (1.0f / CC) - m * m + 1e-5f);
    float o0 = (p.x - m) * rs * ug.x + ub.x;
    float o1 = (p.y - m) * rs * ug.y + ub.y;
    float o2 = (p.z - m) * rs * ug.z + ub.z;
    float o3 = (p.w - m) * rs * ug.w + ub.w;
    float x0 = xv.x + xs0 + gsg * o0;
    float x1 = xv.y + xs1 + gsg * o1;
    float x2 = xv.z + xs2 + gsg * o2;
    float x3 = xv.w + xs3 + gsg * o3;
    *(float4*)(X + off) = make_float4(x0, x1, x2, x3);
    float s2 = x0 + x1 + x2 + x3;
    float sq2 = x0 * x0 + x1 * x1 + x2 * x2 + x3 * x3;
    s2 = wsum(s2); sq2 = wsum(sq2);
    float m2 = s2 * (1.0f / CC);
    float rs2 = rsqrtf(sq2 * (1.0f / CC) - m2 * m2 + 1e-5f);
    ushort4 o;
    o.x = f2bf((x0 - m2) * rs2 * g2.x + b2.x);
    o.y = f2bf((x1 - m2) * rs2 * g2.y + b2.y);
    o.z = f2bf((x2 - m2) * rs2 * g2.z + b2.z);
    o.w = f2bf((x3 - m2) * rs2 * g2.w + b2.w);
    *(ushort4*)(Aout + off) = o;
  }
}

// ---- spatial attention, HEAD-LOOP: one block per (b,t) frame, 8 heads sequential. ----
__global__ __launch_bounds__(384) void k_sp_attn(const u16* __restrict__ QKV, const u16* __restrict__ adj,
                                                 u16* __restrict__ O) {
  __shared__ __align__(16) u16 Qs[96 * 32];
  __shared__ __align__(16) u16 Ks[96 * 32];
  __shared__ __align__(16) u16 Vt[32 * 104];   // V^T: [dim][token], stride 104
  __shared__ __align__(16) u16 Ss[96 * 104];   // adj then P, stride 104
  int blk = blockIdx.x;
  blk = (blk & 7) * ((int)gridDim.x >> 3) + (blk >> 3);  // XCD-chunked (768 % 8 == 0)
  int t = blk % TT, b = blk / TT;
  long fQ = ((long)(b * TT + t) * EE) * 768;
  long fO = ((long)(b * TT + t) * EE) * CC;
  int tid = threadIdx.x;
  int row = tid >> 2, seg = tid & 3;
  int wv = tid >> 6, lane = tid & 63, lm = lane & 15, quad = lane >> 4;
  long gq0 = fQ + (long)row * 768 + seg * 8;
  uint4 rq = *(const uint4*)(QKV + gq0);
  uint4 rk = *(const uint4*)(QKV + gq0 + 256);
  uint4 rv = *(const uint4*)(QKV + gq0 + 512);
  int cb = seg * 24;
  for (int h = 0; h < 8; ++h) {
    *(uint4*)&Qs[row * 32 + seg * 8] = rq;
    *(uint4*)&Ks[row * 32 + seg * 8] = rk;
    { union { uint4 u; u16 s[8]; } vv; vv.u = rv;
#pragma unroll
      for (int i = 0; i < 8; i++) Vt[(seg * 8 + i) * 104 + row] = vv.s[i]; }
#pragma unroll
    for (int i = 0; i < 3; i++)
      *(uint4*)&Ss[row * 104 + cb + i * 8] = *(const uint4*)(adj + row * 96 + cb + i * 8);
    __syncthreads();
    if (h < 7) {  // T14: prefetch next head's QKV under this head's compute
      long g = gq0 + (h + 1) * 32;
      rq = *(const uint4*)(QKV + g);
      rk = *(const uint4*)(QKV + g + 256);
      rv = *(const uint4*)(QKV + g + 512);
      __builtin_amdgcn_sched_barrier(0);
    }
    bf16x8 aq = *(const bf16x8*)&Qs[(wv * 16 + lm) * 32 + quad * 8];
    f32x4 sc[6];
#pragma unroll
    for (int j = 0; j < 6; j++) {
      bf16x8 bk = *(const bf16x8*)&Ks[(j * 16 + lm) * 32 + quad * 8];
      f32x4 z = (f32x4){0.f, 0.f, 0.f, 0.f};
      sc[j] = __builtin_amdgcn_mfma_f32_16x16x32_bf16(aq, bk, z, 0, 0, 0);
    }
    u16 sv[6][4];
#pragma unroll
    for (int j = 0; j < 6; j++) {
      int col = j * 16 + lm;
#pragma unroll
      for (int r = 0; r < 4; r++) {
        int rrow = wv * 16 + quad * 4 + r;
        float a = bf2f(Ss[rrow * 104 + col]);
        sv[j][r] = f2bf((sc[j][r] * a + 1.0f) * 0.5f);
      }
    }
    __syncthreads();
#pragma unroll
    for (int j = 0; j < 6; j++) {
      int col = j * 16 + lm;
#pragma unroll
      for (int r = 0; r < 4; r++) Ss[(wv * 16 + quad * 4 + r) * 104 + col] = sv[j][r];
    }
    __syncthreads();
    f32x4 oc[2];
    oc[0] = (f32x4){0.f, 0.f, 0.f, 0.f};
    oc[1] = (f32x4){0.f, 0.f, 0.f, 0.f};
#pragma unroll
    for (int ks = 0; ks < 3; ks++) {
      bf16x8 as = *(const bf16x8*)&Ss[(wv * 16 + lm) * 104 + ks * 32 + quad * 8];
#pragma unroll
      for (int n = 0; n < 2; n++) {
        bf16x8 bv = *(const bf16x8*)&Vt[(n * 16 + lm) * 104 + ks * 32 + quad * 8];
        oc[n] = __builtin_amdgcn_mfma_f32_16x16x32_bf16(as, bv, oc[n], 0, 0, 0);
      }
    }
#pragma unroll
    for (int n = 0; n < 2; n++)
#pragma unroll
      for (int r = 0; r < 4; r++) {
        int rrow = wv * 16 + quad * 4 + r;
        O[fO + (long)rrow * CC + h * DDm + n * 16 + lm] = f2bf(oc[n][r]);
      }
    __syncthreads();
  }
}

// ---- temporal attention, HEAD-LOOP: one block per (b,e); register softmax per head. ----
__global__ __launch_bounds__(384) void k_tp_attn(const u16* __restrict__ QKV, u16* __restrict__ O) {
  __shared__ __align__(16) u16 Qs[96 * 32];
  __shared__ __align__(16) u16 Ks[96 * 32];
  __shared__ __align__(16) u16 Vt[32 * 104];   // V^T: [dim][token]
  __shared__ __align__(16) u16 Ss[96 * 104];   // P in bf16, stride 104
  int blk = blockIdx.x;
  blk = (blk & 7) * ((int)gridDim.x >> 3) + (blk >> 3);  // XCD-chunked
  int e = blk % EE, b = blk / EE;
  long fQ = ((long)(b * EE + e) * TT) * 768;
  long fO = ((long)(b * EE + e) * TT) * CC;
  int tid = threadIdx.x;
  int row = tid >> 2, seg = tid & 3;
  int wv = tid >> 6, lane = tid & 63, lm = lane & 15, quad = lane >> 4;
  long gq0 = fQ + (long)row * 768 + seg * 8;
  uint4 rq = *(const uint4*)(QKV + gq0);
  uint4 rk = *(const uint4*)(QKV + gq0 + 256);
  uint4 rv = *(const uint4*)(QKV + gq0 + 512);
  const float scale = 0.17677669529663687f;  // 1/sqrt(32)
  for (int h = 0; h < 8; ++h) {
    *(uint4*)&Qs[row * 32 + seg * 8] = rq;
    *(uint4*)&Ks[row * 32 + seg * 8] = rk;
    { union { uint4 u; u16 s[8]; } vv; vv.u = rv;
#pragma unroll
      for (int i = 0; i < 8; i++) Vt[(seg * 8 + i) * 104 + row] = vv.s[i]; }
    __syncthreads();
    if (h < 7) {
      long g = gq0 + (h + 1) * 32;
      rq = *(const uint4*)(QKV + g);
      rk = *(const uint4*)(QKV + g + 256);
      rv = *(const uint4*)(QKV + g + 512);
      __builtin_amdgcn_sched_barrier(0);
    }
    bf16x8 aq = *(const bf16x8*)&Qs[(wv * 16 + lm) * 32 + quad * 8];
    f32x4 sc[6];
#pragma unroll
    for (int j = 0; j < 6; j++) {
      bf16x8 bk = *(const bf16x8*)&Ks[(j * 16 + lm) * 32 + quad * 8];
      f32x4 z = (f32x4){0.f, 0.f, 0.f, 0.f};
      sc[j] = __builtin_amdgcn_mfma_f32_16x16x32_bf16(aq, bk, z, 0, 0, 0);
    }
#pragma unroll
    for (int r = 0; r < 4; r++) {
      float mx = -1e30f;
#pragma unroll
      for (int j = 0; j < 6; j++) { sc[j][r] *= scale; mx = fmaxf(mx, sc[j][r]); }
#pragma unroll
      for (int mask = 1; mask < 16; mask <<= 1) mx = fmaxf(mx, __shfl_xor(mx, mask));
      float sum = 0.f;
#pragma unroll
      for (int j = 0; j < 6; j++) { float p = __expf(sc[j][r] - mx); sc[j][r] = p; sum += p; }
#pragma unroll
      for (int mask = 1; mask < 16; mask <<= 1) sum += __shfl_xor(sum, mask);
      float inv = 1.0f / sum;
#pragma unroll
      for (int j = 0; j < 6; j++) sc[j][r] *= inv;
    }
#pragma unroll
    for (int j = 0; j < 6; j++) {
      int col = j * 16 + lm;
#pragma unroll
      for (int r = 0; r < 4; r++) Ss[(wv * 16 + quad * 4 + r) * 104 + col] = f2bf(sc[j][r]);
    }
    __syncthreads();
    f32x4 oc[2];
    oc[0] = (f32x4){0.f, 0.f, 0.f, 0.f};
    oc[1] = (f32x4){0.f, 0.f, 0.f, 0.f};
#pragma unroll
    for (int ks = 0; ks < 3; ks++) {
      bf16x8 as = *(const bf16x8*)&Ss[(wv * 16 + lm) * 104 + ks * 32 + quad * 8];
#pragma unroll
      for (int n = 0; n < 2; n++) {
        bf16x8 bv = *(const bf16x8*)&Vt[(n * 16 + lm) * 104 + ks * 32 + quad * 8];
        oc[n] = __builtin_amdgcn_mfma_f32_16x16x32_bf16(as, bv, oc[n], 0, 0, 0);
      }
    }
#pragma unroll
    for (int n = 0; n < 2; n++)
#pragma unroll
      for (int r = 0; r < 4; r++) {
        int rrow = wv * 16 + quad * 4 + r;  // t index
        O[fO + (long)rrow * CC + h * DDm + n * 16 + lm] = f2bf(oc[n][r]);
      }
    __syncthreads();
  }
}

// ------- downsample: out[b,i,e,c] = 0.5*(X[b,2i,e,c] + X[b,2i+1,e,c])  (fp32 out) -------
__global__ __launch_bounds__(256) void k_down(const float* __restrict__ X, float* __restrict__ out) {
  long i4 = ((long)blockIdx.x * 256 + threadIdx.x) * 4;
  long tmp = i4;
  int c = (int)(tmp & 255); tmp >>= 8;
  int e = (int)(tmp % EE); tmp /= EE;
  int i = (int)(tmp % TOUT);
  int b = (int)(tmp / TOUT);
  long src0 = (((long)b * TT + 2 * i) * EE + e) * CC + c;
  float4 a = *(const float4*)(X + src0);
  float4 bb = *(const float4*)(X + src0 + (long)EE * CC);
  float4 o = make_float4(0.5f * (a.x + bb.x), 0.5f * (a.y + bb.y),
                         0.5f * (a.z + bb.z), 0.5f * (a.w + bb.w));
  *(float4*)(out + i4) = o;
}

extern "C" void kernel_launch(void* const* d_in, const int* in_sizes, int n_in,
                              void* d_out, int out_size, void* d_ws, size_t ws_size,
                              hipStream_t stream) {
  (void)in_sizes; (void)n_in; (void)out_size; (void)ws_size;
  const float* x   = (const float*)d_in[0];
  const float* adj = (const float*)d_in[1];
  const float* n1g = (const float*)d_in[2];
  const float* n1b = (const float*)d_in[3];
  const float* swq = (const float*)d_in[4];
  const float* swk = (const float*)d_in[5];
  const float* swv = (const float*)d_in[6];
  const float* swp = (const float*)d_in[7];
  const float* sbp = (const float*)d_in[8];
  const float* sng = (const float*)d_in[9];
  const float* snb = (const float*)d_in[10];
  const float* sg  = (const float*)d_in[11];
  const float* n2g = (const float*)d_in[12];
  const float* n2b = (const float*)d_in[13];
  const float* twq = (const float*)d_in[14];
  const float* twk = (const float*)d_in[15];
  const float* twv = (const float*)d_in[16];
  const float* twp = (const float*)d_in[17];
  const float* tbp = (const float*)d_in[18];
  const float* tg  = (const float*)d_in[19];
  const float* n3g = (const float*)d_in[20];
  const float* n3b = (const float*)d_in[21];
  const float* mw1 = (const float*)d_in[22];
  const float* mb1 = (const float*)d_in[23];
  const float* mw2 = (const float*)d_in[24];
  const float* mb2 = (const float*)d_in[25];
  float* out = (float*)d_out;

  // ---- workspace: X fp32 | A bf16 | QKV bf16 [N,768] | weights ----
  size_t nc = (size_t)NTOK * CC;
  float* X  = (float*)d_ws;
  u16* A    = (u16*)(X + nc);
  u16* QKV  = A + nc;
  u16* Hh   = QKV;    // MLP: [N/2, 1024] = 75.5 MB fits in QKV (113 MB)
  u16* wts  = QKV + 3 * nc;
  u16* swq_t = wts;
  u16* swp_t = wts + 3 * 65536;
  u16* twq_t = wts + 4 * 65536;
  u16* twp_t = wts + 7 * 65536;
  u16* w1_t  = wts + 8 * 65536;  // [1024,256]
  u16* w2_t  = w1_t + 262144;    // [256,1024]
  u16* adj_b = w2_t + 262144;    // [96,96]

  WPtr8 w8; w8.p[0] = swq; w8.p[1] = swk; w8.p[2] = swv; w8.p[3] = swp;
  w8.p[4] = twq; w8.p[5] = twk; w8.p[6] = twv; w8.p[7] = twp;
  k_transpose8<<<dim3(256, 8), 256, 0, stream>>>(w8, wts);
  k_transpose<<<(256 * 1024 + 255) / 256, 256, 0, stream>>>(mw1, w1_t, 256, 1024, 256 * 1024);
  k_transpose<<<(1024 * 256 + 255) / 256, 256, 0, stream>>>(mw2, w2_t, 1024, 256, 1024 * 256);
  k_cvt<<<(EE * EE + 255) / 256, 256, 0, stream>>>(adj, adj_b, EE * EE);

  auto gemm = [&](const u16* act, const u16* Wt, const float* bias, const float* gamma,
                  u16* outB, float* Xacc, int Kd, int Nc, int lda, int ldb, int epi, int remap, int M) {
    dim3 g(Nc / 128, M / 128);
    k_gemm128<<<g, 256, 0, stream>>>(act, Wt, bias, gamma, outB, Xacc, Kd, Nc, lda, ldb, epi, remap);
  };

  int lnBlocks = NTOK / 4;

  // ---- spatial block ----
  k_ln_in<<<lnBlocks, 256, 0, stream>>>(x, A, n1g, n1b);                          // A = xs
  gemm(A, swq_t, nullptr, nullptr, QKV, nullptr, 256, 768, 256, 256, 0, 0, NTOK); // fused QKV
  k_sp_attn<<<BB * TT, 384, 0, stream>>>(QKV, adj_b, A);                          // O -> A (head loop)
  // fused proj + combine: P = A@swp+sbp (LDS only); X = x + LN1(x) + sg*LN(P); A = LN2(X)
  k_projcmb<<<NTOK / 128, 512, 0, stream>>>(A, swp_t, sbp, x, X, A,
                                            n1g, n1b, sg, sng, snb, n2g, n2b);

  // ---- temporal block (token order [b,e,t] inside) ----
  gemm(A, twq_t, nullptr, nullptr, QKV, nullptr, 256, 768, 256, 256, 0, 1, NTOK); // fused QKV, bte->bet
  k_tp_attn<<<BB * EE, 384, 0, stream>>>(QKV, A);                                 // O -> A (bet, head loop)
  gemm(A, twp_t, tbp, tg, nullptr, X, 256, 256, 256, 256, 3, 2, NTOK);            // X += g*(O@wp+b), bet->bte

  // ---- MLP: token-split halves, full HID=1024 each (X RMW once per token) ----
  k_ln_f32<<<lnBlocks, 256, 0, stream>>>(X, A, n3g, n3b);                         // A = xm
  for (int hf = 0; hf < 2; hf++) {
    long r0 = (long)hf * (NTOK / 2);
    gemm(A + r0 * CC, w1_t, mb1, nullptr, Hh, nullptr, 256, 1024, 256, 256, 2, 0, NTOK / 2);
    gemm(Hh, w2_t, mb2, nullptr, nullptr, X + r0 * CC, 1024, 256, 1024, 1024, 3, 0, NTOK / 2);
  }

  // ---- downsample (fp32 out) ----
  long outElems = (long)BB * TOUT * EE * CC;
  k_down<<<(int)(outElems / 4 / 256), 256, 0, stream>>>(X, out);
}